// Round 9
// baseline (498.469 us; speedup 1.0000x reference)
//
#include <hip/hip_runtime.h>
#include <hip/hip_bf16.h>

// ---------------------------------------------------------------------------
// SSGraphDTI forward. bf16 MFMA convs + collapsed-affine GNN, fp32 FC head.
// R9: double-buffered LDS staging in conv bodies (1 barrier/chunk, global
// staging overlapped with MFMA) — conv kernels are latency-bound at ~21%
// occupancy, 2-barrier/chunk lockstep was the stall. Rest identical to R8.
// ---------------------------------------------------------------------------

typedef __attribute__((ext_vector_type(8))) short short8;
typedef __attribute__((ext_vector_type(4))) float f32x4;
union FragU { uint32_t u[4]; uint4 q; short8 s; };

static __device__ inline unsigned short f2bf(float v) {
    __hip_bfloat16 h = __float2bfloat16(v);
    return *(unsigned short*)&h;
}

// ---------------- workspace layout (byte offsets) ----------------
static constexpr size_t O_PAIR = 0;            // 64*1420 f32
static constexpr size_t O_CF1  = 363520;       // 64*1024 f32
static constexpr size_t O_CF2  = 625664;       // 64*1024 f32
static constexpr size_t O_CF3  = 887808;       // 64*512 f32 -> 1,018,880
static constexpr size_t O_BD   = 1018880;      // 128 f32
static constexpr size_t O_BP   = 1019392;      // 1024 f32
static constexpr size_t O_WDS  = 1023488;      // 128x1248 bf16
static constexpr size_t O_WPS  = 1342976;      // 1024x2208 bf16
static constexpr size_t O_WTP1 = 5864960;      // 64x512 bf16
static constexpr size_t O_WTP2 = 5930496;      // 128x320 bf16
static constexpr size_t O_WTP3 = 6012416;      // 192x1280 bf16
static constexpr size_t O_WTD1 = 6503936;      // 64x512 bf16
static constexpr size_t O_WTD2 = 6569472;      // 128x320 bf16
static constexpr size_t O_WTD3 = 6651392;      // 192x640 bf16
static constexpr size_t AR     = 6897152;      // aliased region base
// GNN phase:
static constexpr size_t A_AD  = AR + 0;        // 192x1248 bf16 = 479,232
static constexpr size_t A_AP  = AR + 479232;   // 192x2208 bf16 = 847,872
static constexpr size_t A_A2D = AR + 1327104;  // 64x1248 bf16
static constexpr size_t A_A2P = AR + 1486848;  // 64x2208 bf16
static constexpr size_t A_UD  = AR + 1769472;  // 192x112 f32
static constexpr size_t A_UP  = AR + 1855488;  // 192x1024 f32
static constexpr size_t A_RHO = AR + 2641920;  // 64x4 f32 -> AR+2,642,944
// conv phase aliases (GNN dead by then):
static constexpr size_t A_Y2P = AR + 0;          // 64x80x992 bf16 = 10,158,080
static constexpr size_t A_Y1P = AR + 10158080;   // 64x40x1000 bf16 = 5,120,000
static constexpr size_t A_Y1D = AR + 15278080;   // 64x40x104 bf16 = 532,480
static constexpr size_t A_Y2D = AR + 15810560;   // 64x80x96 bf16 = 983,040
static constexpr size_t NEED_BYTES = AR + 16793600;  // 23,690,752

// ---------------------------------------------------------------------------
__global__ void zero32_k(uint32_t* __restrict__ p, int n) {
    int i = blockIdx.x * 256 + threadIdx.x;
    if (i < n) p[i] = 0u;
}

// ---------------- fused prep: weights + biases + biasfill + all zeroing ----
static constexpr long Q0 = 100;                 // bd
static constexpr long Q1 = Q0 + 1000;           // bp
static constexpr long Q2 = Q1 + 14336;          // WdS[0:112) = ddi_Wl
static constexpr long Q3 = Q2 + 14336;          // WdS[112:224) = ddi_Wr+pdi_Wr
static constexpr long Q4 = Q3 + 131072;         // WdS[224:1248) = pdi_Wl
static constexpr long Q5 = Q4 + 1048576;        // WpS[0:1024) = ppi_Wl
static constexpr long Q6 = Q5 + 1048576;        // WpS[1024:2048) = ppi_Wr+dpi_Wr
static constexpr long Q7 = Q6 + 163840;         // WpS[2048:2208) = dpi_Wl
static constexpr long Q8 = Q7 + 32768;          // WtP1
static constexpr long Q9 = Q8 + 40960;          // WtP2
static constexpr long Q10 = Q9 + 245760;        // WtP3
static constexpr long Q11 = Q10 + 32768;        // WtD1
static constexpr long Q12 = Q11 + 40960;        // WtD2
static constexpr long Q13 = Q12 + 122880;       // WtD3
static constexpr long Q14 = Q13 + 70400;        // pair biasfill cols[320:1420)
static constexpr long Q15 = Q14 + 20480;        // pair zero cols[0:320)
static constexpr long Q16 = Q15 + 163840;       // cf1..cf3 zero
static constexpr long Q17 = Q16 + 660736;       // GNN region zero

__device__ inline void wt_block(unsigned short* dst, int ld_dst, int coloff,
                                const float* s1, const float* s2, int ld_src,
                                int N, int Kreal, int Kblk, long local) {
    int n = (int)(local / Kblk), k = (int)(local % Kblk);
    float v = 0.f;
    if (n < N && k < Kreal) {
        v = s1[(size_t)n * ld_src + k];
        if (s2) v += s2[(size_t)n * ld_src + k];
    }
    dst[(size_t)n * ld_dst + coloff + k] = f2bf(v);
}

__device__ inline void wtconv_block(unsigned short* dst, const float* W,
                                    int Co, int Ci, int K, int KP, long local) {
    int co = (int)(local / (Ci * KP));
    int rem = (int)(local % (Ci * KP));
    int ci = rem / KP, k = rem % KP;
    float v = (co < Co && k < K) ? W[((size_t)co * Ci + ci) * K + k] : 0.f;
    dst[local] = f2bf(v);
}

__global__ __launch_bounds__(256) void prep_k(
    float* bd, float* bp, unsigned short* WdS, unsigned short* WpS,
    unsigned short* WtP1, unsigned short* WtP2, unsigned short* WtP3,
    unsigned short* WtD1, unsigned short* WtD2, unsigned short* WtD3,
    float* pair, float* cfz, uint32_t* gnnz,
    const float* ddi_Wl, const float* ddi_bl, const float* ddi_Wr,
    const float* ppi_Wl, const float* ppi_bl, const float* ppi_Wr,
    const float* dpi_Wl, const float* dpi_bl, const float* dpi_Wr,
    const float* pdi_Wl, const float* pdi_bl, const float* pdi_Wr,
    const float* dW1, const float* dW2, const float* dW3,
    const float* pW1, const float* pW2, const float* pW3) {
    long idx = (long)blockIdx.x * 256 + threadIdx.x;
    if (idx < Q0) { bd[idx] = 0.5f * (ddi_bl[idx] + pdi_bl[idx]); return; }
    if (idx < Q1) { long j = idx - Q0; bp[j] = 0.5f * (ppi_bl[j] + dpi_bl[j]); return; }
    if (idx < Q2) { wt_block(WdS, 1248, 0, ddi_Wl, nullptr, 100, 100, 100, 112, idx - Q1); return; }
    if (idx < Q3) { wt_block(WdS, 1248, 112, ddi_Wr, pdi_Wr, 100, 100, 100, 112, idx - Q2); return; }
    if (idx < Q4) { wt_block(WdS, 1248, 224, pdi_Wl, nullptr, 1000, 100, 1000, 1024, idx - Q3); return; }
    if (idx < Q5) { wt_block(WpS, 2208, 0, ppi_Wl, nullptr, 1000, 1000, 1000, 1024, idx - Q4); return; }
    if (idx < Q6) { wt_block(WpS, 2208, 1024, ppi_Wr, dpi_Wr, 1000, 1000, 1000, 1024, idx - Q5); return; }
    if (idx < Q7) { wt_block(WpS, 2208, 2048, dpi_Wl, nullptr, 100, 1000, 100, 160, idx - Q6); return; }
    if (idx < Q8)  { wtconv_block(WtP1, pW1, 40, 64, 4, 8, idx - Q7); return; }
    if (idx < Q9)  { wtconv_block(WtP2, pW2, 80, 40, 8, 8, idx - Q8); return; }
    if (idx < Q10) { wtconv_block(WtP3, pW3, 160, 80, 12, 16, idx - Q9); return; }
    if (idx < Q11) { wtconv_block(WtD1, dW1, 40, 64, 4, 8, idx - Q10); return; }
    if (idx < Q12) { wtconv_block(WtD2, dW2, 80, 40, 6, 8, idx - Q11); return; }
    if (idx < Q13) { wtconv_block(WtD3, dW3, 160, 80, 8, 8, idx - Q12); return; }
    if (idx < Q14) {
        long l = idx - Q13;
        int b = (int)(l / 1100), j = (int)(l % 1100);
        if (j < 100) pair[(size_t)b * 1420 + 320 + j] = 0.5f * (ddi_bl[j] + pdi_bl[j]);
        else { int j2 = j - 100; pair[(size_t)b * 1420 + 420 + j2] = 0.5f * (ppi_bl[j2] + dpi_bl[j2]); }
        return;
    }
    if (idx < Q15) {
        long l = idx - Q14;
        int b = (int)(l / 320), j = (int)(l % 320);
        pair[(size_t)b * 1420 + j] = 0.f;
        return;
    }
    if (idx < Q16) { cfz[idx - Q15] = 0.f; return; }
    if (idx < Q17) { gnnz[idx - Q16] = 0u; return; }
}

// ---------------------------------------------------------------------------
// GNN front-end (verified R6): edges -> 2-hop weights -> histogram -> F slots.
__global__ __launch_bounds__(256) void gnn_front_k(const int* __restrict__ ddi,
                                                   const int* __restrict__ ppi,
                                                   const int* __restrict__ dpi,
                                                   const int* __restrict__ dtoks,
                                                   const int* __restrict__ ptoks,
                                                   const float* __restrict__ dtable,
                                                   const float* __restrict__ ptable,
                                                   float* __restrict__ RHO,
                                                   unsigned short* __restrict__ Ad,
                                                   unsigned short* __restrict__ Ap) {
    const int role = blockIdx.x, b = blockIdx.y, tid = threadIdx.x;
    __shared__ float M[4][32][32];
    __shared__ int cnt4[4][32];
    __shared__ float inv4[4][32];
    __shared__ float W7[7][32];
    __shared__ int cnt[32][72];
    __shared__ float WC[7][72];
    for (int i = tid; i < 4 * 32 * 32; i += 256) ((float*)M)[i] = 0.f;
    if (tid < 128) ((int*)cnt4)[tid] = 0;
    __syncthreads();
    const int* ed = ddi + (size_t)b * 256;
    const int* ep = ppi + (size_t)b * 256;
    const int* ex = dpi + (size_t)b * 128;
    if (tid < 128) {
        atomicAdd(&cnt4[0][ed[128 + tid]], 1);
        atomicAdd(&cnt4[1][ep[128 + tid]], 1);
    } else if (tid < 192) {
        int e = tid - 128;
        atomicAdd(&cnt4[2][ex[e]], 1);
        atomicAdd(&cnt4[3][ex[64 + e]], 1);
    }
    __syncthreads();
    if (tid < 128) {
        int which = tid >> 5, j = tid & 31;
        inv4[which][j] = 1.f / (float)max(cnt4[which][j], 1);
    }
    __syncthreads();
    if (tid < 128) {
        int s = ed[tid], d = ed[128 + tid];
        atomicAdd(&M[0][d][s], inv4[0][d]);
        int s2 = ep[tid], d2 = ep[128 + tid];
        atomicAdd(&M[1][d2][s2], inv4[1][d2]);
    } else if (tid < 192) {
        int e = tid - 128;
        int dr = ex[e], pr = ex[64 + e];
        atomicAdd(&M[2][dr][pr], inv4[2][dr]);
        atomicAdd(&M[3][pr][dr], inv4[3][pr]);
    }
    __syncthreads();
    if (tid < 32) {
        int j = tid;
        if (role == 0) {
            float r1 = 0.f, r4 = 0.f, r5 = 0.f, r7 = 0.f;
            for (int k = 0; k < 32; ++k) {
                r1 += M[0][0][k] * M[0][k][j];
                r4 += M[2][0][k] * M[3][k][j];
                r5 += M[1][0][k] * M[3][k][j];
                r7 += M[3][0][k] * M[0][k][j];
            }
            W7[0][j] = r1; W7[1][j] = M[0][0][j]; W7[2][j] = (j == 0) ? 1.f : 0.f;
            W7[3][j] = r4; W7[4][j] = r5; W7[5][j] = M[3][0][j]; W7[6][j] = r7;
        } else {
            float s1 = 0.f, s3 = 0.f, s4 = 0.f, s7 = 0.f;
            for (int k = 0; k < 32; ++k) {
                s1 += M[0][0][k] * M[2][k][j];
                s3 += M[2][0][k] * M[1][k][j];
                s4 += M[1][0][k] * M[1][k][j];
                s7 += M[3][0][k] * M[2][k][j];
            }
            W7[0][j] = s1; W7[1][j] = M[2][0][j]; W7[2][j] = s3;
            W7[3][j] = s4; W7[4][j] = M[1][0][j];
            W7[5][j] = (j == 0) ? 1.f : 0.f; W7[6][j] = s7;
        }
    }
    if (role == 0 && tid == 0) {
        float a = 0.f, bq = 0.f, cq = 0.f, dq = 0.f;
        for (int k = 0; k < 32; ++k) {
            a += M[0][0][k]; bq += M[2][0][k]; cq += M[1][0][k]; dq += M[3][0][k];
        }
        RHO[b * 4 + 0] = a; RHO[b * 4 + 1] = bq; RHO[b * 4 + 2] = cq; RHO[b * 4 + 3] = dq;
    }
    const int V = role ? 26 : 71;
    const int L = role ? 1000 : 100;
    for (int i = tid; i < 32 * 72; i += 256) ((int*)cnt)[i] = 0;
    __syncthreads();
    const int* tk = (role ? ptoks : dtoks) + (size_t)b * 32 * L;
    for (int i = tid; i < 32 * L; i += 256) atomicAdd(&cnt[i / L][tk[i]], 1);
    __syncthreads();
    float invL = 1.f / (float)L;
    for (int o = tid; o < 7 * V; o += 256) {
        int i = o / V, v = o % V;
        float a = 0.f;
        for (int k = 0; k < 32; ++k) a += W7[i][k] * (float)cnt[k][v];
        WC[i][v] = a * invL;
    }
    __syncthreads();
    size_t g0d = (size_t)b * 1248, g1d_ = (size_t)(64 + b) * 1248, g2d = (size_t)(128 + b) * 1248;
    size_t g0p = (size_t)b * 2208, g1p = (size_t)(64 + b) * 2208, g2p = (size_t)(128 + b) * 2208;
    if (role == 0) {
        int d = tid;
        if (d >= 100) return;
        float acc[7] = {};
        for (int v = 0; v < 71; ++v) {
            float tv = dtable[(size_t)v * 100 + d];
            #pragma unroll
            for (int i = 0; i < 7; ++i) acc[i] += WC[i][v] * tv;
        }
        unsigned short h;
        h = f2bf(acc[0]); Ad[g0d + d] = h;
        h = f2bf(acc[1]); Ad[g0d + 112 + d] = h; Ad[g1d_ + d] = h;
        h = f2bf(acc[2]); Ad[g1d_ + 112 + d] = h;
        h = f2bf(acc[3]); Ap[g0p + 2048 + d] = h;
        h = f2bf(acc[4]); Ap[g1p + 2048 + d] = h;
        h = f2bf(acc[5]); Ap[g2p + 2048 + d] = h; Ad[g2d + 112 + d] = h;
        h = f2bf(acc[6]); Ad[g2d + d] = h;
    } else {
        for (int d = tid; d < 1000; d += 256) {
            float acc[7] = {};
            for (int v = 0; v < 26; ++v) {
                float tv = ptable[(size_t)v * 1000 + d];
                #pragma unroll
                for (int i = 0; i < 7; ++i) acc[i] += WC[i][v] * tv;
            }
            unsigned short h;
            h = f2bf(acc[0]); Ad[g0d + 224 + d] = h;
            h = f2bf(acc[1]); Ad[g1d_ + 224 + d] = h; Ap[g0p + 1024 + d] = h;
            h = f2bf(acc[2]); Ap[g0p + d] = h;
            h = f2bf(acc[3]); Ap[g1p + d] = h;
            h = f2bf(acc[4]); Ap[g1p + 1024 + d] = h; Ap[g2p + d] = h;
            h = f2bf(acc[5]); Ap[g2p + 1024 + d] = h;
            h = f2bf(acc[6]); Ad[g2d + 224 + d] = h;
        }
    }
}

// ---------------------------------------------------------------------------
// skinny bf16 MFMA GEMM body (split-K + m-group), atomicAdd fp32 out.
__device__ __forceinline__ void sk_body(const unsigned short* __restrict__ A, int lda,
                                        const unsigned short* __restrict__ Bm, int ldb,
                                        int K, int KS, float scale,
                                        float* __restrict__ out,
                                        int rs, int coloff, int Nw,
                                        int bx, int by, int gz) {
    const int tid = threadIdx.x;
    const int lane = tid & 63, w = tid >> 6, c = lane & 15, q = lane >> 4;
    const int n = bx * 64 + w * 16 + c;
    const unsigned short* Ab = A + (size_t)gz * 64 * lda;
    const int Ks = ((K / KS + 31) / 32) * 32;
    const int k0 = by * Ks;
    const int k1 = min(K, k0 + Ks);
    f32x4 acc[4];
    #pragma unroll
    for (int i = 0; i < 4; ++i) acc[i] = (f32x4){0.f, 0.f, 0.f, 0.f};
    for (int k = k0; k < k1; k += 32) {
        FragU bf;
        bf.q = *(const uint4*)&Bm[(size_t)n * ldb + k + q * 8];
        #pragma unroll
        for (int i = 0; i < 4; ++i) {
            FragU af;
            af.q = *(const uint4*)&Ab[(size_t)(i * 16 + c) * lda + k + q * 8];
            acc[i] = __builtin_amdgcn_mfma_f32_16x16x32_bf16(af.s, bf.s, acc[i], 0, 0, 0);
        }
    }
    if (n >= Nw) return;
    #pragma unroll
    for (int i = 0; i < 4; ++i)
        #pragma unroll
        for (int r = 0; r < 4; ++r) {
            int m = gz * 64 + i * 16 + q * 4 + r;
            atomicAdd(&out[(size_t)m * rs + coloff + n], scale * acc[i][r]);
        }
}

// stage-1: z<3 protein groups, z>=3 drug groups (x<2). grid (16,8,6)
__global__ __launch_bounds__(256) void sk_stage1(const unsigned short* __restrict__ Ad,
                                                 const unsigned short* __restrict__ WdS,
                                                 float* __restrict__ Ud,
                                                 const unsigned short* __restrict__ Ap,
                                                 const unsigned short* __restrict__ WpS,
                                                 float* __restrict__ Up) {
    int z = blockIdx.z;
    if (z < 3) {
        sk_body(Ap, 2208, WpS, 2208, 2208, 8, 0.5f, Up, 1024, 0, 1000,
                blockIdx.x, blockIdx.y, z);
    } else {
        if (blockIdx.x >= 2) return;
        sk_body(Ad, 1248, WdS, 1248, 1248, 8, 0.5f, Ud, 112, 0, 100,
                blockIdx.x, blockIdx.y, z - 3);
    }
}

// stage-2: z==0 protein -> pair[420:], z==1 drug (x<2) -> pair[320:]. grid (16,8,2)
__global__ __launch_bounds__(256) void sk_stage2(const unsigned short* __restrict__ A2d,
                                                 const unsigned short* __restrict__ WdS,
                                                 const unsigned short* __restrict__ A2p,
                                                 const unsigned short* __restrict__ WpS,
                                                 float* __restrict__ pair) {
    int z = blockIdx.z;
    if (z == 0) {
        sk_body(A2p, 2208, WpS, 2208, 2208, 8, 0.5f, pair, 1420, 420, 1000,
                blockIdx.x, blockIdx.y, 0);
    } else {
        if (blockIdx.x >= 2) return;
        sk_body(A2d, 1248, WdS, 1248, 1248, 8, 0.5f, pair, 1420, 320, 100,
                blockIdx.x, blockIdx.y, 0);
    }
}

// merged stage-1 epilogue: Ud/Up + rho*bias -> bf16 A2 slots
__global__ void ep_k(const float* __restrict__ Ud, const float* __restrict__ Up,
                     const float* __restrict__ RHO,
                     const float* __restrict__ bd, const float* __restrict__ bp,
                     unsigned short* __restrict__ A2d, unsigned short* __restrict__ A2p) {
    int idx = blockIdx.x * 256 + threadIdx.x;
    if (idx < 192 * 112) {
        int m = idx / 112, n = idx % 112;
        if (n >= 100) return;
        int g = m >> 6, b = m & 63;
        float rho = (g == 0) ? RHO[b * 4 + 0] : (g == 1) ? 1.f : RHO[b * 4 + 3];
        unsigned short h = f2bf(Ud[idx] + rho * bd[n]);
        if (g == 0) A2d[(size_t)b * 1248 + n] = h;
        else if (g == 1) A2d[(size_t)b * 1248 + 112 + n] = h;
        else A2p[(size_t)b * 2208 + 2048 + n] = h;
    } else {
        int l = idx - 192 * 112;
        if (l >= 192 * 1024) return;
        int m = l / 1024, n = l % 1024;
        if (n >= 1000) return;
        int g = m >> 6, b = m & 63;
        float rho = (g == 0) ? RHO[b * 4 + 1] : (g == 1) ? RHO[b * 4 + 2] : 1.f;
        unsigned short h = f2bf(Up[l] + rho * bp[n]);
        if (g == 0) A2d[(size_t)b * 1248 + 224 + n] = h;
        else if (g == 1) A2p[(size_t)b * 2208 + n] = h;
        else A2p[(size_t)b * 2208 + 1024 + n] = h;
    }
}

// ---------------------------------------------------------------------------
// conv1d implicit-GEMM bf16 MFMA body, ITILE=4, double-buffered LDS staging.
// As: 2 x 64*72 shorts, xraw: 2 x CIPC*272 shorts.
template <int KP>
__device__ __forceinline__ void conv_body(const unsigned short* __restrict__ xin,
                                          int Ci, int Lp,
                                          const unsigned short* __restrict__ Wt, int KK,
                                          int nchunk,
                                          const float* __restrict__ bias, int Co,
                                          unsigned short* __restrict__ yout,
                                          int Lout, int LoutPad,
                                          float* __restrict__ pool, int pool_coloff,
                                          int b, int co0, int t0,
                                          unsigned short* As, unsigned short* xraw) {
    constexpr int CIPC = 64 / KP;
    constexpr int LG = (KP == 8) ? 3 : 4;
    const int tid = threadIdx.x;
    const int lane = tid & 63, w = tid >> 6, c = lane & 15, q = lane >> 4;
    f32x4 acc[4][4];
    #pragma unroll
    for (int i = 0; i < 4; ++i)
        #pragma unroll
        for (int j = 0; j < 4; ++j) acc[i][j] = (f32x4){0.f, 0.f, 0.f, 0.f};
    const int row8 = tid >> 3, col8 = (tid & 7) * 8;

    auto stage = [&](int ch, int buf) {
        unsigned short* Asb = As + buf * (64 * 72);
        unsigned short* xb = xraw + buf * (CIPC * 272);
        const int kkbase = ch * 64, ci0 = ch * CIPC;
        #pragma unroll
        for (int p = 0; p < 2; ++p) {
            int row = row8 + p * 32;
            *(uint4*)&Asb[row * 72 + col8] =
                *(const uint4*)&Wt[(size_t)(co0 + row) * KK + kkbase + col8];
        }
        for (int gi = tid; gi < CIPC * 34; gi += 256) {
            int ci = gi / 34, g8 = (gi % 34) * 8, gt = t0 + g8;
            const unsigned short* src = xin + ((size_t)b * Ci + ci0 + ci) * Lp + gt;
            if (gt + 8 <= Lp) {
                *(uint4*)&xb[ci * 272 + g8] = *(const uint4*)src;
            } else {
                #pragma unroll
                for (int jj = 0; jj < 8; ++jj)
                    xb[ci * 272 + g8 + jj] = (gt + jj < Lp) ? src[jj] : (unsigned short)0;
            }
        }
    };

    stage(0, 0);
    __syncthreads();
    for (int ch = 0; ch < nchunk; ++ch) {
        const int cur = ch & 1;
        if (ch + 1 < nchunk) stage(ch + 1, cur ^ 1);  // overlap with compute
        const unsigned short* Asb = As + cur * (64 * 72);
        const uint32_t* xbase = (const uint32_t*)(xraw + cur * (CIPC * 272));
        #pragma unroll
        for (int ks = 0; ks < 2; ++ks) {
            const int kc = ks * 32;
            FragU af[4];
            #pragma unroll
            for (int i = 0; i < 4; ++i)
                af[i].q = *(const uint4*)&Asb[(i * 16 + c) * 72 + kc + q * 8];
            const int koff = kc + q * 8;
            const int cioff = koff >> LG;
            const int k0 = koff & (KP - 1);
            const uint32_t* xr = xbase + cioff * 136;
            #pragma unroll
            for (int j = 0; j < 4; ++j) {
                int tt = w * 64 + j * 16 + c;
                int eoff = tt + k0;
                int d0 = eoff >> 1;
                unsigned sh = (unsigned)(eoff & 1) * 16u;
                uint32_t u0 = xr[d0], u1 = xr[d0 + 1], u2 = xr[d0 + 2],
                         u3 = xr[d0 + 3], u4 = xr[d0 + 4];
                FragU bf;
                bf.u[0] = __builtin_amdgcn_alignbit(u1, u0, sh);
                bf.u[1] = __builtin_amdgcn_alignbit(u2, u1, sh);
                bf.u[2] = __builtin_amdgcn_alignbit(u3, u2, sh);
                bf.u[3] = __builtin_amdgcn_alignbit(u4, u3, sh);
                #pragma unroll
                for (int i = 0; i < 4; ++i)
                    acc[i][j] = __builtin_amdgcn_mfma_f32_16x16x32_bf16(af[i].s, bf.s,
                                                                        acc[i][j], 0, 0, 0);
            }
        }
        __syncthreads();
    }
    if (pool) {
        #pragma unroll
        for (int i = 0; i < 4; ++i) {
            #pragma unroll
            for (int r = 0; r < 4; ++r) {
                int co = co0 + i * 16 + q * 4 + r;
                float bv = (co < Co) ? bias[co] : 0.f;
                float v = 0.f;
                #pragma unroll
                for (int j = 0; j < 4; ++j) {
                    int t = t0 + w * 64 + j * 16 + c;
                    if (t < Lout) v = fmaxf(v, fmaxf(acc[i][j][r] + bv, 0.f));
                }
                v = fmaxf(v, __shfl_xor(v, 1));
                v = fmaxf(v, __shfl_xor(v, 2));
                v = fmaxf(v, __shfl_xor(v, 4));
                v = fmaxf(v, __shfl_xor(v, 8));
                if (c == 0 && co < Co)
                    atomicMax((int*)&pool[(size_t)b * 1420 + pool_coloff + co],
                              __float_as_int(v));
            }
        }
    } else {
        #pragma unroll
        for (int i = 0; i < 4; ++i) {
            #pragma unroll
            for (int r = 0; r < 4; ++r) {
                int co = co0 + i * 16 + q * 4 + r;
                if (co >= Co) continue;
                float bv = bias[co];
                #pragma unroll
                for (int j = 0; j < 4; ++j) {
                    int t = t0 + w * 64 + j * 16 + c;
                    if (t < Lout) {
                        yout[((size_t)b * Co + co) * LoutPad + t] =
                            f2bf(fmaxf(acc[i][j][r] + bv, 0.f));
                    } else if (t < LoutPad) {
                        yout[((size_t)b * Co + co) * LoutPad + t] = 0;
                    }
                }
            }
        }
    }
}

// conv1 with fused embedding lookup (V <= 71). KP=8, Ci=64, ITILE=4, dbuf.
__device__ __forceinline__ void conv1e_body(const int* __restrict__ toks,
                                            const float* __restrict__ table, int V, int L,
                                            const unsigned short* __restrict__ Wt, int KK,
                                            const float* __restrict__ bias, int Co,
                                            unsigned short* __restrict__ yout,
                                            int Lout, int LoutPad,
                                            int b, int co0, int t0,
                                            unsigned short* As, unsigned short* xraw,
                                            unsigned short* tabT, int* tok_s) {
    const int tid = threadIdx.x;
    const int lane = tid & 63, w = tid >> 6, c = lane & 15, q = lane >> 4;
    for (int idx = tid; idx < 64 * V; idx += 256) {
        int ci = idx / V, v = idx % V;
        tabT[ci * 72 + v] = f2bf(table[(size_t)v * 64 + ci]);
    }
    for (int t = tid; t < 272; t += 256) {
        int gt = t0 + t;
        tok_s[t] = (gt < L) ? toks[(size_t)b * L + gt] : 0;  // row 0 is zeros
    }
    __syncthreads();
    f32x4 acc[4][4];
    #pragma unroll
    for (int i = 0; i < 4; ++i)
        #pragma unroll
        for (int j = 0; j < 4; ++j) acc[i][j] = (f32x4){0.f, 0.f, 0.f, 0.f};
    const int row8 = tid >> 3, col8 = (tid & 7) * 8;

    auto stage = [&](int ch, int buf) {
        unsigned short* Asb = As + buf * (64 * 72);
        unsigned short* xb = xraw + buf * (8 * 272);
        const int kkbase = ch * 64, ci0 = ch * 8;
        #pragma unroll
        for (int p = 0; p < 2; ++p) {
            int row = row8 + p * 32;
            *(uint4*)&Asb[row * 72 + col8] =
                *(const uint4*)&Wt[(size_t)(co0 + row) * KK + kkbase + col8];
        }
        for (int gi = tid; gi < 8 * 272; gi += 256) {
            int ci = gi / 272, t = gi % 272;
            xb[gi] = tabT[(ci0 + ci) * 72 + tok_s[t]];
        }
    };

    stage(0, 0);
    __syncthreads();
    for (int ch = 0; ch < 8; ++ch) {
        const int cur = ch & 1;
        if (ch + 1 < 8) stage(ch + 1, cur ^ 1);
        const unsigned short* Asb = As + cur * (64 * 72);
        const uint32_t* xbase = (const uint32_t*)(xraw + cur * (8 * 272));
        #pragma unroll
        for (int ks = 0; ks < 2; ++ks) {
            const int kc = ks * 32;
            FragU af[4];
            #pragma unroll
            for (int i = 0; i < 4; ++i)
                af[i].q = *(const uint4*)&Asb[(i * 16 + c) * 72 + kc + q * 8];
            const int koff = kc + q * 8;
            const int cioff = koff >> 3;
            const uint32_t* xr = xbase + cioff * 136;
            #pragma unroll
            for (int j = 0; j < 4; ++j) {
                int tt = w * 64 + j * 16 + c;
                int d0 = tt >> 1;
                unsigned sh = (unsigned)(tt & 1) * 16u;
                uint32_t u0 = xr[d0], u1 = xr[d0 + 1], u2 = xr[d0 + 2],
                         u3 = xr[d0 + 3], u4 = xr[d0 + 4];
                FragU bf;
                bf.u[0] = __builtin_amdgcn_alignbit(u1, u0, sh);
                bf.u[1] = __builtin_amdgcn_alignbit(u2, u1, sh);
                bf.u[2] = __builtin_amdgcn_alignbit(u3, u2, sh);
                bf.u[3] = __builtin_amdgcn_alignbit(u4, u3, sh);
                #pragma unroll
                for (int i = 0; i < 4; ++i)
                    acc[i][j] = __builtin_amdgcn_mfma_f32_16x16x32_bf16(af[i].s, bf.s,
                                                                        acc[i][j], 0, 0, 0);
            }
        }
        __syncthreads();
    }
    #pragma unroll
    for (int i = 0; i < 4; ++i) {
        #pragma unroll
        for (int r = 0; r < 4; ++r) {
            int co = co0 + i * 16 + q * 4 + r;
            if (co >= Co) continue;
            float bv = bias[co];
            #pragma unroll
            for (int j = 0; j < 4; ++j) {
                int t = t0 + w * 64 + j * 16 + c;
                if (t < Lout) {
                    yout[((size_t)b * Co + co) * LoutPad + t] =
                        f2bf(fmaxf(acc[i][j][r] + bv, 0.f));
                } else if (t < LoutPad) {
                    yout[((size_t)b * Co + co) * LoutPad + t] = 0;
                }
            }
        }
    }
}

// conv1 dual: z<64 protein, z>=64 drug (x==0 only). grid (4,1,128)
__global__ __launch_bounds__(256) void conv1_dual(
    const int* __restrict__ ptoks, const float* __restrict__ ptable,
    const unsigned short* __restrict__ WtP1, const float* __restrict__ pb1,
    unsigned short* __restrict__ y1p,
    const int* __restrict__ dtoks, const float* __restrict__ dtable,
    const unsigned short* __restrict__ WtD1, const float* __restrict__ db1,
    unsigned short* __restrict__ y1d) {
    __shared__ __align__(16) unsigned short As[2 * 64 * 72];
    __shared__ __align__(16) unsigned short xraw[2 * 8 * 272];
    __shared__ unsigned short tabT[64 * 72];
    __shared__ int tok_s[272];
    int z = blockIdx.z;
    if (z < 64) {
        conv1e_body(ptoks, ptable, 26, 1000, WtP1, 512, pb1, 40, y1p, 997, 1000,
                    z, 0, blockIdx.x * 256, As, xraw, tabT, tok_s);
    } else {
        if (blockIdx.x > 0) return;
        conv1e_body(dtoks, dtable, 71, 100, WtD1, 512, db1, 40, y1d, 97, 104,
                    z - 64, 0, 0, As, xraw, tabT, tok_s);
    }
}

// conv2 dual (ITILE=4): z<64 protein conv2 (Co=80, y co-blocks), z>=64 drug
// conv2 (x==0). grid (4,2,128)
__global__ __launch_bounds__(256) void conv2_dual(
    const unsigned short* __restrict__ y1p, const unsigned short* __restrict__ WtP2,
    const float* __restrict__ pb2, unsigned short* __restrict__ y2p,
    const unsigned short* __restrict__ y1d, const unsigned short* __restrict__ WtD2,
    const float* __restrict__ db2, unsigned short* __restrict__ y2d) {
    __shared__ __align__(16) unsigned short As[2 * 64 * 72];
    __shared__ __align__(16) unsigned short xraw[2 * 8 * 272];
    int z = blockIdx.z;
    if (z < 64) {
        conv_body<8>(y1p, 40, 1000, WtP2, 320, 5, pb2, 80, y2p, 990, 992,
                     nullptr, 0, z, blockIdx.y * 64, blockIdx.x * 256, As, xraw);
    } else {
        if (blockIdx.x > 0) return;
        conv_body<8>(y1d, 40, 104, WtD2, 320, 5, db2, 80, y2d, 92, 96,
                     nullptr, 0, z - 64, blockIdx.y * 64, 0, As, xraw);
    }
}

// conv3 dual (pool, ITILE=4): z<64 protein conv3 (KP=16), z>=64 drug conv3
// (KP=8, x==0). grid (4,3,128)
__global__ __launch_bounds__(256) void conv3_dual(
    const unsigned short* __restrict__ y2p, const unsigned short* __restrict__ WtP3,
    const float* __restrict__ pb3, float* __restrict__ pair,
    const unsigned short* __restrict__ y2d, const unsigned short* __restrict__ WtD3,
    const float* __restrict__ db3) {
    __shared__ __align__(16) unsigned short As[2 * 64 * 72];
    __shared__ __align__(16) unsigned short xraw[2 * 8 * 272];
    int z = blockIdx.z;
    if (z < 64) {
        conv_body<16>(y2p, 80, 992, WtP3, 1280, 20, pb3, 160, nullptr, 979, 0,
                      pair, 160, z, blockIdx.y * 64, blockIdx.x * 256, As, xraw);
    } else {
        if (blockIdx.x > 0) return;
        conv_body<8>(y2d, 80, 96, WtD3, 640, 10, db3, 160, nullptr, 85, 0,
                     pair, 0, z - 64, blockIdx.y * 64, 0, As, xraw);
    }
}

// ---------------------------------------------------------------------------
// fp32 NT-SGEMM (FC head), split-K atomic; optional leaky(bias) epilogue
// applied to A on load (fuses the previous layer's activation).
__global__ __launch_bounds__(256) void gemm_nt(const float* __restrict__ A, int lda,
                                               const float* __restrict__ Aep_b,
                                               const float* __restrict__ Bm,
                                               float* __restrict__ Cout,
                                               int M, int N, int K, int KC) {
    const int m0 = blockIdx.x * 64, n0 = blockIdx.y * 64, s = blockIdx.z;
    const int tid = threadIdx.x, ty = tid >> 4, tx = tid & 15;
    __shared__ __align__(16) float As[16][68];
    __shared__ __align__(16) float Bs[16][68];
    float acc[4][4] = {};
    const int kbeg = s * KC, kend = min(K, kbeg + KC);
    for (int k0 = kbeg; k0 < kend; k0 += 16) {
        int colk = k0 + tx;
        bool kok = colk < kend;
        #pragma unroll
        for (int qq = 0; qq < 4; ++qq) {
            int mi = ty + qq * 16;
            float va = 0.f;
            if (kok && (m0 + mi) < M) {
                va = A[(size_t)(m0 + mi) * lda + colk];
                if (Aep_b) {
                    va += Aep_b[colk];
                    va = va >= 0.f ? va : 0.01f * va;
                }
            }
            As[tx][mi] = va;
            Bs[tx][mi] = (kok && (n0 + mi) < N) ? Bm[(size_t)(n0 + mi) * K + colk] : 0.f;
        }
        __syncthreads();
        #pragma unroll
        for (int kk = 0; kk < 16; ++kk) {
            float4 a4 = *(const float4*)&As[kk][ty * 4];
            float4 b4 = *(const float4*)&Bs[kk][tx * 4];
            float av[4] = {a4.x, a4.y, a4.z, a4.w};
            float bv[4] = {b4.x, b4.y, b4.z, b4.w};
            #pragma unroll
            for (int i = 0; i < 4; ++i)
                #pragma unroll
                for (int j = 0; j < 4; ++j)
                    acc[i][j] = fmaf(av[i], bv[j], acc[i][j]);
        }
        __syncthreads();
    }
    #pragma unroll
    for (int i = 0; i < 4; ++i) {
        int m = m0 + ty * 4 + i;
        if (m >= M) continue;
        #pragma unroll
        for (int j = 0; j < 4; ++j) {
            int n = n0 + tx * 4 + j;
            if (n >= N) continue;
            atomicAdd(&Cout[(size_t)m * N + n], acc[i][j]);
        }
    }
}

// final: leaky(cf3 + b3) @ out_W^T + out_b
__global__ void out_k(const float* __restrict__ cf3, const float* __restrict__ b3,
                      const float* __restrict__ W, const float* __restrict__ bias,
                      float* __restrict__ out) {
    int tid = threadIdx.x;
    if (tid >= 128) return;
    int b = tid >> 1, n = tid & 1;
    const float* hr = cf3 + (size_t)b * 512;
    const float* wr = W + (size_t)n * 512;
    float a = 0.f;
    for (int k = 0; k < 512; ++k) {
        float v = hr[k] + b3[k];
        v = v >= 0.f ? v : 0.01f * v;
        a = fmaf(v, wr[k], a);
    }
    out[b * 2 + n] = a + bias[n];
}

// ---------------------------------------------------------------------------
static inline int kc_of(int K, int S) { return ((K + S * 16 - 1) / (S * 16)) * 16; }
static inline dim3 g1d(int n) { return dim3((n + 255) / 256); }

extern "C" void kernel_launch(void* const* d_in, const int* in_sizes, int n_in,
                              void* d_out, int out_size, void* d_ws, size_t ws_size,
                              hipStream_t stream) {
    const int* drug_tokens       = (const int*)d_in[0];
    const int* protein_tokens    = (const int*)d_in[1];
    const int* drug_node_tokens  = (const int*)d_in[2];
    const int* protein_node_toks = (const int*)d_in[3];
    const int* ddi_edges         = (const int*)d_in[4];
    const int* ppi_edges         = (const int*)d_in[5];
    const int* dpi_edges         = (const int*)d_in[6];
    const float* drug_embed      = (const float*)d_in[7];
    const float* protein_embed   = (const float*)d_in[8];
    const float* dW1 = (const float*)d_in[9];  const float* db1 = (const float*)d_in[10];
    const float* dW2 = (const float*)d_in[11]; const float* db2 = (const float*)d_in[12];
    const float* dW3 = (const float*)d_in[13]; const float* db3 = (const float*)d_in[14];
    const float* pW1 = (const float*)d_in[15]; const float* pb1 = (const float*)d_in[16];
    const float* pW2 = (const float*)d_in[17]; const float* pb2 = (const float*)d_in[18];
    const float* pW3 = (const float*)d_in[19]; const float* pb3 = (const float*)d_in[20];
    const float* drug_node_table = (const float*)d_in[21];
    const float* prot_node_table = (const float*)d_in[22];
    const float* ddi_Wl = (const float*)d_in[23]; const float* ddi_bl = (const float*)d_in[24];
    const float* ddi_Wr = (const float*)d_in[25];
    const float* ppi_Wl = (const float*)d_in[26]; const float* ppi_bl = (const float*)d_in[27];
    const float* ppi_Wr = (const float*)d_in[28];
    const float* dpi_Wl = (const float*)d_in[29]; const float* dpi_bl = (const float*)d_in[30];
    const float* dpi_Wr = (const float*)d_in[31];
    const float* pdi_Wl = (const float*)d_in[32]; const float* pdi_bl = (const float*)d_in[33];
    const float* pdi_Wr = (const float*)d_in[34];
    const float* fc1_W = (const float*)d_in[35]; const float* fc1_b = (const float*)d_in[36];
    const float* fc2_W = (const float*)d_in[37]; const float* fc2_b = (const float*)d_in[38];
    const float* fc3_W = (const float*)d_in[39]; const float* fc3_b = (const float*)d_in[40];
    const float* out_W = (const float*)d_in[41]; const float* out_b = (const float*)d_in[42];

    float* outp = (float*)d_out;
    if (ws_size < NEED_BYTES) {
        zero32_k<<<g1d(out_size), 256, 0, stream>>>((uint32_t*)outp, out_size);
        return;
    }
    char* wsb = (char*)d_ws;
    float* pair = (float*)(wsb + O_PAIR);
    float* cf1 = (float*)(wsb + O_CF1); float* cf2 = (float*)(wsb + O_CF2);
    float* cf3 = (float*)(wsb + O_CF3);
    float* bd = (float*)(wsb + O_BD); float* bp = (float*)(wsb + O_BP);
    unsigned short* WdS  = (unsigned short*)(wsb + O_WDS);
    unsigned short* WpS  = (unsigned short*)(wsb + O_WPS);
    unsigned short* WtP1 = (unsigned short*)(wsb + O_WTP1);
    unsigned short* WtP2 = (unsigned short*)(wsb + O_WTP2);
    unsigned short* WtP3 = (unsigned short*)(wsb + O_WTP3);
    unsigned short* WtD1 = (unsigned short*)(wsb + O_WTD1);
    unsigned short* WtD2 = (unsigned short*)(wsb + O_WTD2);
    unsigned short* WtD3 = (unsigned short*)(wsb + O_WTD3);
    unsigned short* Ad  = (unsigned short*)(wsb + A_AD);
    unsigned short* Ap  = (unsigned short*)(wsb + A_AP);
    unsigned short* A2d = (unsigned short*)(wsb + A_A2D);
    unsigned short* A2p = (unsigned short*)(wsb + A_A2P);
    float* Ud  = (float*)(wsb + A_UD);
    float* Up  = (float*)(wsb + A_UP);
    float* RHO = (float*)(wsb + A_RHO);
    unsigned short* y2p = (unsigned short*)(wsb + A_Y2P);
    unsigned short* y1p = (unsigned short*)(wsb + A_Y1P);
    unsigned short* y1d = (unsigned short*)(wsb + A_Y1D);
    unsigned short* y2d = (unsigned short*)(wsb + A_Y2D);

    // 1) prep: weights + biases + pair biasfill/zero + cf zero + GNN zero
    prep_k<<<g1d((int)Q17), 256, 0, stream>>>(bd, bp, WdS, WpS,
                                              WtP1, WtP2, WtP3, WtD1, WtD2, WtD3,
                                              pair, cf1, (uint32_t*)(wsb + A_AD),
                                              ddi_Wl, ddi_bl, ddi_Wr,
                                              ppi_Wl, ppi_bl, ppi_Wr,
                                              dpi_Wl, dpi_bl, dpi_Wr,
                                              pdi_Wl, pdi_bl, pdi_Wr,
                                              dW1, dW2, dW3, pW1, pW2, pW3);

    // 2) GNN front-end
    gnn_front_k<<<dim3(2, 64), 256, 0, stream>>>(ddi_edges, ppi_edges, dpi_edges,
                                                 drug_node_tokens, protein_node_toks,
                                                 drug_node_table, prot_node_table,
                                                 RHO, Ad, Ap);

    // 3) GNN stage 1 (merged d+p) -> ep -> stage 2 (merged d+p)
    sk_stage1<<<dim3(16, 8, 6), 256, 0, stream>>>(Ad, WdS, Ud, Ap, WpS, Up);
    ep_k<<<g1d(192 * 112 + 192 * 1024), 256, 0, stream>>>(Ud, Up, RHO, bd, bp, A2d, A2p);
    sk_stage2<<<dim3(16, 8, 2), 256, 0, stream>>>(A2d, WdS, A2p, WpS, pair);

    // 4) conv towers (dual-dispatch, ITILE=4, double-buffered LDS)
    conv1_dual<<<dim3(4, 1, 128), 256, 0, stream>>>(protein_tokens, protein_embed,
                                                    WtP1, pb1, y1p,
                                                    drug_tokens, drug_embed,
                                                    WtD1, db1, y1d);
    conv2_dual<<<dim3(4, 2, 128), 256, 0, stream>>>(y1p, WtP2, pb2, y2p,
                                                    y1d, WtD2, db2, y2d);
    conv3_dual<<<dim3(4, 3, 128), 256, 0, stream>>>(y2p, WtP3, pb3, pair,
                                                    y2d, WtD3, db3);

    // 5) FC head (fp32, split-K 16; leaky+bias fused into next gemm's A-load)
    gemm_nt<<<dim3(1, 16, 16), 256, 0, stream>>>(pair, 1420, nullptr, fc1_W, cf1,
                                                 64, 1024, 1420, kc_of(1420, 16));
    gemm_nt<<<dim3(1, 16, 16), 256, 0, stream>>>(cf1, 1024, fc1_b, fc2_W, cf2,
                                                 64, 1024, 1024, kc_of(1024, 16));
    gemm_nt<<<dim3(1, 8, 16), 256, 0, stream>>>(cf2, 1024, fc2_b, fc3_W, cf3,
                                                64, 512, 1024, kc_of(1024, 16));
    out_k<<<dim3(1), 128, 0, stream>>>(cf3, fc3_b, out_W, out_b, outp);
}

// Round 10
// 466.360 us; speedup vs baseline: 1.0688x; 1.0688x over previous
//
#include <hip/hip_runtime.h>
#include <hip/hip_bf16.h>

// ---------------------------------------------------------------------------
// SSGraphDTI forward. bf16 MFMA convs + collapsed-affine GNN, fp32 FC head.
// R10: revert R9 dbuf (occupancy regression). Co-dispatch independent GNN and
// conv stages in merged 1-D-grid kernels (GNN chain hides under conv chain).
// Layout branches on ws_size: overlapped (26.3MB) if it fits, else R8 serial.
// ---------------------------------------------------------------------------

typedef __attribute__((ext_vector_type(8))) short short8;
typedef __attribute__((ext_vector_type(4))) float f32x4;
union FragU { uint32_t u[4]; uint4 q; short8 s; };

static __device__ inline unsigned short f2bf(float v) {
    __hip_bfloat16 h = __float2bfloat16(v);
    return *(unsigned short*)&h;
}

// ---------------- workspace layout (byte offsets) ----------------
static constexpr size_t O_PAIR = 0;            // 64*1420 f32
static constexpr size_t O_CF1  = 363520;       // 64*1024 f32
static constexpr size_t O_CF2  = 625664;       // 64*1024 f32
static constexpr size_t O_CF3  = 887808;       // 64*512 f32 -> 1,018,880
static constexpr size_t O_BD   = 1018880;      // 128 f32
static constexpr size_t O_BP   = 1019392;      // 1024 f32
static constexpr size_t O_WDS  = 1023488;      // 128x1248 bf16
static constexpr size_t O_WPS  = 1342976;      // 1024x2208 bf16
static constexpr size_t O_WTP1 = 5864960;      // 64x512 bf16
static constexpr size_t O_WTP2 = 5930496;      // 128x320 bf16
static constexpr size_t O_WTP3 = 6012416;      // 192x1280 bf16
static constexpr size_t O_WTD1 = 6503936;      // 64x512 bf16
static constexpr size_t O_WTD2 = 6569472;      // 128x320 bf16
static constexpr size_t O_WTD3 = 6651392;      // 192x640 bf16
static constexpr size_t AR     = 6897152;      // aliased region base
// GNN region (same in both layouts):
static constexpr size_t A_AD  = AR + 0;        // 192x1248 bf16 = 479,232
static constexpr size_t A_AP  = AR + 479232;   // 192x2208 bf16 = 847,872
static constexpr size_t A_A2D = AR + 1327104;  // 64x1248 bf16
static constexpr size_t A_A2P = AR + 1486848;  // 64x2208 bf16
static constexpr size_t A_UD  = AR + 1769472;  // 192x112 f32
static constexpr size_t A_UP  = AR + 1855488;  // 192x1024 f32
static constexpr size_t A_RHO = AR + 2641920;  // 64x4 f32 -> AR+2,642,944
static constexpr size_t GNN_END = AR + 2642944;
// conv sizes:
static constexpr size_t SZ_Y2P = 10158080;     // 64x80x992 bf16
static constexpr size_t SZ_Y1P = 5120000;      // 64x40x1000 bf16
static constexpr size_t SZ_Y1D = 532480;       // 64x40x104 bf16
static constexpr size_t SZ_Y2D = 983040;       // 64x80x96 bf16
static constexpr size_t NEED_FB   = AR + SZ_Y2P + SZ_Y1P + SZ_Y1D + SZ_Y2D; // 23,690,752 (proven)
static constexpr size_t NEED_FULL = GNN_END + SZ_Y2P + SZ_Y1P + SZ_Y1D + SZ_Y2D; // 26,333,696

// ---------------------------------------------------------------------------
__global__ void zero32_k(uint32_t* __restrict__ p, int n) {
    int i = blockIdx.x * 256 + threadIdx.x;
    if (i < n) p[i] = 0u;
}

// ---------------- fused prep: weights + biases + biasfill + all zeroing ----
static constexpr long Q0 = 100;
static constexpr long Q1 = Q0 + 1000;
static constexpr long Q2 = Q1 + 14336;
static constexpr long Q3 = Q2 + 14336;
static constexpr long Q4 = Q3 + 131072;
static constexpr long Q5 = Q4 + 1048576;
static constexpr long Q6 = Q5 + 1048576;
static constexpr long Q7 = Q6 + 163840;
static constexpr long Q8 = Q7 + 32768;
static constexpr long Q9 = Q8 + 40960;
static constexpr long Q10 = Q9 + 245760;
static constexpr long Q11 = Q10 + 32768;
static constexpr long Q12 = Q11 + 40960;
static constexpr long Q13 = Q12 + 122880;
static constexpr long Q14 = Q13 + 70400;
static constexpr long Q15 = Q14 + 20480;
static constexpr long Q16 = Q15 + 163840;
static constexpr long Q17 = Q16 + 660736;

__device__ inline void wt_block(unsigned short* dst, int ld_dst, int coloff,
                                const float* s1, const float* s2, int ld_src,
                                int N, int Kreal, int Kblk, long local) {
    int n = (int)(local / Kblk), k = (int)(local % Kblk);
    float v = 0.f;
    if (n < N && k < Kreal) {
        v = s1[(size_t)n * ld_src + k];
        if (s2) v += s2[(size_t)n * ld_src + k];
    }
    dst[(size_t)n * ld_dst + coloff + k] = f2bf(v);
}

__device__ inline void wtconv_block(unsigned short* dst, const float* W,
                                    int Co, int Ci, int K, int KP, long local) {
    int co = (int)(local / (Ci * KP));
    int rem = (int)(local % (Ci * KP));
    int ci = rem / KP, k = rem % KP;
    float v = (co < Co && k < K) ? W[((size_t)co * Ci + ci) * K + k] : 0.f;
    dst[local] = f2bf(v);
}

__global__ __launch_bounds__(256) void prep_k(
    float* bd, float* bp, unsigned short* WdS, unsigned short* WpS,
    unsigned short* WtP1, unsigned short* WtP2, unsigned short* WtP3,
    unsigned short* WtD1, unsigned short* WtD2, unsigned short* WtD3,
    float* pair, float* cfz, uint32_t* gnnz,
    const float* ddi_Wl, const float* ddi_bl, const float* ddi_Wr,
    const float* ppi_Wl, const float* ppi_bl, const float* ppi_Wr,
    const float* dpi_Wl, const float* dpi_bl, const float* dpi_Wr,
    const float* pdi_Wl, const float* pdi_bl, const float* pdi_Wr,
    const float* dW1, const float* dW2, const float* dW3,
    const float* pW1, const float* pW2, const float* pW3) {
    long idx = (long)blockIdx.x * 256 + threadIdx.x;
    if (idx < Q0) { bd[idx] = 0.5f * (ddi_bl[idx] + pdi_bl[idx]); return; }
    if (idx < Q1) { long j = idx - Q0; bp[j] = 0.5f * (ppi_bl[j] + dpi_bl[j]); return; }
    if (idx < Q2) { wt_block(WdS, 1248, 0, ddi_Wl, nullptr, 100, 100, 100, 112, idx - Q1); return; }
    if (idx < Q3) { wt_block(WdS, 1248, 112, ddi_Wr, pdi_Wr, 100, 100, 100, 112, idx - Q2); return; }
    if (idx < Q4) { wt_block(WdS, 1248, 224, pdi_Wl, nullptr, 1000, 100, 1000, 1024, idx - Q3); return; }
    if (idx < Q5) { wt_block(WpS, 2208, 0, ppi_Wl, nullptr, 1000, 1000, 1000, 1024, idx - Q4); return; }
    if (idx < Q6) { wt_block(WpS, 2208, 1024, ppi_Wr, dpi_Wr, 1000, 1000, 1000, 1024, idx - Q5); return; }
    if (idx < Q7) { wt_block(WpS, 2208, 2048, dpi_Wl, nullptr, 100, 1000, 100, 160, idx - Q6); return; }
    if (idx < Q8)  { wtconv_block(WtP1, pW1, 40, 64, 4, 8, idx - Q7); return; }
    if (idx < Q9)  { wtconv_block(WtP2, pW2, 80, 40, 8, 8, idx - Q8); return; }
    if (idx < Q10) { wtconv_block(WtP3, pW3, 160, 80, 12, 16, idx - Q9); return; }
    if (idx < Q11) { wtconv_block(WtD1, dW1, 40, 64, 4, 8, idx - Q10); return; }
    if (idx < Q12) { wtconv_block(WtD2, dW2, 80, 40, 6, 8, idx - Q11); return; }
    if (idx < Q13) { wtconv_block(WtD3, dW3, 160, 80, 8, 8, idx - Q12); return; }
    if (idx < Q14) {
        long l = idx - Q13;
        int b = (int)(l / 1100), j = (int)(l % 1100);
        if (j < 100) pair[(size_t)b * 1420 + 320 + j] = 0.5f * (ddi_bl[j] + pdi_bl[j]);
        else { int j2 = j - 100; pair[(size_t)b * 1420 + 420 + j2] = 0.5f * (ppi_bl[j2] + dpi_bl[j2]); }
        return;
    }
    if (idx < Q15) {
        long l = idx - Q14;
        int b = (int)(l / 320), j = (int)(l % 320);
        pair[(size_t)b * 1420 + j] = 0.f;
        return;
    }
    if (idx < Q16) { cfz[idx - Q15] = 0.f; return; }
    if (idx < Q17) { gnnz[idx - Q16] = 0u; return; }
}

// ---------------------------------------------------------------------------
// GNN front-end body (verified R6 logic), LDS carved from pool (29,536 B).
__device__ void gnn_front_body(const int* __restrict__ ddi, const int* __restrict__ ppi,
                               const int* __restrict__ dpi,
                               const int* __restrict__ dtoks, const int* __restrict__ ptoks,
                               const float* __restrict__ dtable, const float* __restrict__ ptable,
                               float* __restrict__ RHO,
                               unsigned short* __restrict__ Ad, unsigned short* __restrict__ Ap,
                               int role, int b, char* pool) {
    const int tid = threadIdx.x;
    float* M    = (float*)pool;              // 4*32*32 f32
    int*   cnt4 = (int*)(pool + 16384);      // 4*32
    float* inv4 = (float*)(pool + 16896);    // 4*32
    float* W7   = (float*)(pool + 17408);    // 7*32
    int*   cnt  = (int*)(pool + 18304);      // 32*72
    float* WC   = (float*)(pool + 27520);    // 7*72
    for (int i = tid; i < 4 * 32 * 32; i += 256) M[i] = 0.f;
    if (tid < 128) cnt4[tid] = 0;
    __syncthreads();
    const int* ed = ddi + (size_t)b * 256;
    const int* ep = ppi + (size_t)b * 256;
    const int* ex = dpi + (size_t)b * 128;
    if (tid < 128) {
        atomicAdd(&cnt4[0 * 32 + ed[128 + tid]], 1);
        atomicAdd(&cnt4[1 * 32 + ep[128 + tid]], 1);
    } else if (tid < 192) {
        int e = tid - 128;
        atomicAdd(&cnt4[2 * 32 + ex[e]], 1);
        atomicAdd(&cnt4[3 * 32 + ex[64 + e]], 1);
    }
    __syncthreads();
    if (tid < 128) inv4[tid] = 1.f / (float)max(cnt4[tid], 1);
    __syncthreads();
    if (tid < 128) {
        int s = ed[tid], d = ed[128 + tid];
        atomicAdd(&M[0 * 1024 + d * 32 + s], inv4[0 * 32 + d]);
        int s2 = ep[tid], d2 = ep[128 + tid];
        atomicAdd(&M[1 * 1024 + d2 * 32 + s2], inv4[1 * 32 + d2]);
    } else if (tid < 192) {
        int e = tid - 128;
        int dr = ex[e], pr = ex[64 + e];
        atomicAdd(&M[2 * 1024 + dr * 32 + pr], inv4[2 * 32 + dr]);
        atomicAdd(&M[3 * 1024 + pr * 32 + dr], inv4[3 * 32 + pr]);
    }
    __syncthreads();
    if (tid < 32) {
        int j = tid;
        if (role == 0) {
            float r1 = 0.f, r4 = 0.f, r5 = 0.f, r7 = 0.f;
            for (int k = 0; k < 32; ++k) {
                r1 += M[0 * 1024 + 0 * 32 + k] * M[0 * 1024 + k * 32 + j];
                r4 += M[2 * 1024 + 0 * 32 + k] * M[3 * 1024 + k * 32 + j];
                r5 += M[1 * 1024 + 0 * 32 + k] * M[3 * 1024 + k * 32 + j];
                r7 += M[3 * 1024 + 0 * 32 + k] * M[0 * 1024 + k * 32 + j];
            }
            W7[0 * 32 + j] = r1; W7[1 * 32 + j] = M[0 * 1024 + j];
            W7[2 * 32 + j] = (j == 0) ? 1.f : 0.f;
            W7[3 * 32 + j] = r4; W7[4 * 32 + j] = r5;
            W7[5 * 32 + j] = M[3 * 1024 + j]; W7[6 * 32 + j] = r7;
        } else {
            float s1 = 0.f, s3 = 0.f, s4 = 0.f, s7 = 0.f;
            for (int k = 0; k < 32; ++k) {
                s1 += M[0 * 1024 + 0 * 32 + k] * M[2 * 1024 + k * 32 + j];
                s3 += M[2 * 1024 + 0 * 32 + k] * M[1 * 1024 + k * 32 + j];
                s4 += M[1 * 1024 + 0 * 32 + k] * M[1 * 1024 + k * 32 + j];
                s7 += M[3 * 1024 + 0 * 32 + k] * M[2 * 1024 + k * 32 + j];
            }
            W7[0 * 32 + j] = s1; W7[1 * 32 + j] = M[2 * 1024 + j];
            W7[2 * 32 + j] = s3; W7[3 * 32 + j] = s4;
            W7[4 * 32 + j] = M[1 * 1024 + j];
            W7[5 * 32 + j] = (j == 0) ? 1.f : 0.f; W7[6 * 32 + j] = s7;
        }
    }
    if (role == 0 && tid == 0) {
        float a = 0.f, bq = 0.f, cq = 0.f, dq = 0.f;
        for (int k = 0; k < 32; ++k) {
            a += M[0 * 1024 + k]; bq += M[2 * 1024 + k];
            cq += M[1 * 1024 + k]; dq += M[3 * 1024 + k];
        }
        RHO[b * 4 + 0] = a; RHO[b * 4 + 1] = bq; RHO[b * 4 + 2] = cq; RHO[b * 4 + 3] = dq;
    }
    const int V = role ? 26 : 71;
    const int L = role ? 1000 : 100;
    for (int i = tid; i < 32 * 72; i += 256) cnt[i] = 0;
    __syncthreads();
    const int* tk = (role ? ptoks : dtoks) + (size_t)b * 32 * L;
    for (int i = tid; i < 32 * L; i += 256) atomicAdd(&cnt[(i / L) * 72 + tk[i]], 1);
    __syncthreads();
    float invL = 1.f / (float)L;
    for (int o = tid; o < 7 * V; o += 256) {
        int i = o / V, v = o % V;
        float a = 0.f;
        for (int k = 0; k < 32; ++k) a += W7[i * 32 + k] * (float)cnt[k * 72 + v];
        WC[i * 72 + v] = a * invL;
    }
    __syncthreads();
    size_t g0d = (size_t)b * 1248, g1d_ = (size_t)(64 + b) * 1248, g2d = (size_t)(128 + b) * 1248;
    size_t g0p = (size_t)b * 2208, g1p = (size_t)(64 + b) * 2208, g2p = (size_t)(128 + b) * 2208;
    if (role == 0) {
        int d = tid;
        if (d >= 100) return;
        float acc[7] = {};
        for (int v = 0; v < 71; ++v) {
            float tv = dtable[(size_t)v * 100 + d];
            #pragma unroll
            for (int i = 0; i < 7; ++i) acc[i] += WC[i * 72 + v] * tv;
        }
        unsigned short h;
        h = f2bf(acc[0]); Ad[g0d + d] = h;
        h = f2bf(acc[1]); Ad[g0d + 112 + d] = h; Ad[g1d_ + d] = h;
        h = f2bf(acc[2]); Ad[g1d_ + 112 + d] = h;
        h = f2bf(acc[3]); Ap[g0p + 2048 + d] = h;
        h = f2bf(acc[4]); Ap[g1p + 2048 + d] = h;
        h = f2bf(acc[5]); Ap[g2p + 2048 + d] = h; Ad[g2d + 112 + d] = h;
        h = f2bf(acc[6]); Ad[g2d + d] = h;
    } else {
        for (int d = tid; d < 1000; d += 256) {
            float acc[7] = {};
            for (int v = 0; v < 26; ++v) {
                float tv = ptable[(size_t)v * 1000 + d];
                #pragma unroll
                for (int i = 0; i < 7; ++i) acc[i] += WC[i * 72 + v] * tv;
            }
            unsigned short h;
            h = f2bf(acc[0]); Ad[g0d + 224 + d] = h;
            h = f2bf(acc[1]); Ad[g1d_ + 224 + d] = h; Ap[g0p + 1024 + d] = h;
            h = f2bf(acc[2]); Ap[g0p + d] = h;
            h = f2bf(acc[3]); Ap[g1p + d] = h;
            h = f2bf(acc[4]); Ap[g1p + 1024 + d] = h; Ap[g2p + d] = h;
            h = f2bf(acc[5]); Ap[g2p + 1024 + d] = h;
            h = f2bf(acc[6]); Ad[g2d + 224 + d] = h;
        }
    }
}

// ---------------------------------------------------------------------------
// skinny bf16 MFMA GEMM body (split-K + m-group), atomicAdd fp32 out. No LDS.
__device__ __forceinline__ void sk_body(const unsigned short* __restrict__ A, int lda,
                                        const unsigned short* __restrict__ Bm, int ldb,
                                        int K, int KS, float scale,
                                        float* __restrict__ out,
                                        int rs, int coloff, int Nw,
                                        int bx, int by, int gz) {
    const int tid = threadIdx.x;
    const int lane = tid & 63, w = tid >> 6, c = lane & 15, q = lane >> 4;
    const int n = bx * 64 + w * 16 + c;
    const unsigned short* Ab = A + (size_t)gz * 64 * lda;
    const int Ks = ((K / KS + 31) / 32) * 32;
    const int k0 = by * Ks;
    const int k1 = min(K, k0 + Ks);
    f32x4 acc[4];
    #pragma unroll
    for (int i = 0; i < 4; ++i) acc[i] = (f32x4){0.f, 0.f, 0.f, 0.f};
    for (int k = k0; k < k1; k += 32) {
        FragU bf;
        bf.q = *(const uint4*)&Bm[(size_t)n * ldb + k + q * 8];
        #pragma unroll
        for (int i = 0; i < 4; ++i) {
            FragU af;
            af.q = *(const uint4*)&Ab[(size_t)(i * 16 + c) * lda + k + q * 8];
            acc[i] = __builtin_amdgcn_mfma_f32_16x16x32_bf16(af.s, bf.s, acc[i], 0, 0, 0);
        }
    }
    if (n >= Nw) return;
    #pragma unroll
    for (int i = 0; i < 4; ++i)
        #pragma unroll
        for (int r = 0; r < 4; ++r) {
            int m = gz * 64 + i * 16 + q * 4 + r;
            atomicAdd(&out[(size_t)m * rs + coloff + n], scale * acc[i][r]);
        }
}

// ep item: Ud/Up + rho*bias -> bf16 A2 slots
__device__ void ep_item(int idx, const float* __restrict__ Ud, const float* __restrict__ Up,
                        const float* __restrict__ RHO,
                        const float* __restrict__ bd, const float* __restrict__ bp,
                        unsigned short* __restrict__ A2d, unsigned short* __restrict__ A2p) {
    if (idx < 192 * 112) {
        int m = idx / 112, n = idx % 112;
        if (n >= 100) return;
        int g = m >> 6, b = m & 63;
        float rho = (g == 0) ? RHO[b * 4 + 0] : (g == 1) ? 1.f : RHO[b * 4 + 3];
        unsigned short h = f2bf(Ud[idx] + rho * bd[n]);
        if (g == 0) A2d[(size_t)b * 1248 + n] = h;
        else if (g == 1) A2d[(size_t)b * 1248 + 112 + n] = h;
        else A2p[(size_t)b * 2208 + 2048 + n] = h;
    } else {
        int l = idx - 192 * 112;
        if (l >= 192 * 1024) return;
        int m = l / 1024, n = l % 1024;
        if (n >= 1000) return;
        int g = m >> 6, b = m & 63;
        float rho = (g == 0) ? RHO[b * 4 + 1] : (g == 1) ? RHO[b * 4 + 2] : 1.f;
        unsigned short h = f2bf(Up[l] + rho * bp[n]);
        if (g == 0) A2d[(size_t)b * 1248 + 224 + n] = h;
        else if (g == 1) A2p[(size_t)b * 2208 + n] = h;
        else A2p[(size_t)b * 2208 + 1024 + n] = h;
    }
}

// ---------------------------------------------------------------------------
// conv1d implicit-GEMM bf16 MFMA body, ITILE=4, single-buffer (R8 proven).
template <int KP>
__device__ __forceinline__ void conv_body(const unsigned short* __restrict__ xin,
                                          int Ci, int Lp,
                                          const unsigned short* __restrict__ Wt, int KK,
                                          int nchunk,
                                          const float* __restrict__ bias, int Co,
                                          unsigned short* __restrict__ yout,
                                          int Lout, int LoutPad,
                                          float* __restrict__ pool_out, int pool_coloff,
                                          int b, int co0, int t0,
                                          unsigned short* As, unsigned short* xraw) {
    constexpr int CIPC = 64 / KP;
    constexpr int LG = (KP == 8) ? 3 : 4;
    const int tid = threadIdx.x;
    const int lane = tid & 63, w = tid >> 6, c = lane & 15, q = lane >> 4;
    f32x4 acc[4][4];
    #pragma unroll
    for (int i = 0; i < 4; ++i)
        #pragma unroll
        for (int j = 0; j < 4; ++j) acc[i][j] = (f32x4){0.f, 0.f, 0.f, 0.f};
    const int row8 = tid >> 3, col8 = (tid & 7) * 8;
    for (int ch = 0; ch < nchunk; ++ch) {
        const int kkbase = ch * 64, ci0 = ch * CIPC;
        #pragma unroll
        for (int p = 0; p < 2; ++p) {
            int row = row8 + p * 32;
            *(uint4*)&As[row * 72 + col8] =
                *(const uint4*)&Wt[(size_t)(co0 + row) * KK + kkbase + col8];
        }
        for (int gi = tid; gi < CIPC * 34; gi += 256) {
            int ci = gi / 34, g8 = (gi % 34) * 8, gt = t0 + g8;
            const unsigned short* src = xin + ((size_t)b * Ci + ci0 + ci) * Lp + gt;
            if (gt + 8 <= Lp) {
                *(uint4*)&xraw[ci * 272 + g8] = *(const uint4*)src;
            } else {
                #pragma unroll
                for (int jj = 0; jj < 8; ++jj)
                    xraw[ci * 272 + g8 + jj] = (gt + jj < Lp) ? src[jj] : (unsigned short)0;
            }
        }
        __syncthreads();
        #pragma unroll
        for (int ks = 0; ks < 2; ++ks) {
            const int kc = ks * 32;
            FragU af[4];
            #pragma unroll
            for (int i = 0; i < 4; ++i)
                af[i].q = *(const uint4*)&As[(i * 16 + c) * 72 + kc + q * 8];
            const int koff = kc + q * 8;
            const int cioff = koff >> LG;
            const int k0 = koff & (KP - 1);
            const uint32_t* xr = (const uint32_t*)xraw + cioff * 136;
            #pragma unroll
            for (int j = 0; j < 4; ++j) {
                int tt = w * 64 + j * 16 + c;
                int eoff = tt + k0;
                int d0 = eoff >> 1;
                unsigned sh = (unsigned)(eoff & 1) * 16u;
                uint32_t u0 = xr[d0], u1 = xr[d0 + 1], u2 = xr[d0 + 2],
                         u3 = xr[d0 + 3], u4 = xr[d0 + 4];
                FragU bf;
                bf.u[0] = __builtin_amdgcn_alignbit(u1, u0, sh);
                bf.u[1] = __builtin_amdgcn_alignbit(u2, u1, sh);
                bf.u[2] = __builtin_amdgcn_alignbit(u3, u2, sh);
                bf.u[3] = __builtin_amdgcn_alignbit(u4, u3, sh);
                #pragma unroll
                for (int i = 0; i < 4; ++i)
                    acc[i][j] = __builtin_amdgcn_mfma_f32_16x16x32_bf16(af[i].s, bf.s,
                                                                        acc[i][j], 0, 0, 0);
            }
        }
        __syncthreads();
    }
    if (pool_out) {
        #pragma unroll
        for (int i = 0; i < 4; ++i) {
            #pragma unroll
            for (int r = 0; r < 4; ++r) {
                int co = co0 + i * 16 + q * 4 + r;
                float bv = (co < Co) ? bias[co] : 0.f;
                float v = 0.f;
                #pragma unroll
                for (int j = 0; j < 4; ++j) {
                    int t = t0 + w * 64 + j * 16 + c;
                    if (t < Lout) v = fmaxf(v, fmaxf(acc[i][j][r] + bv, 0.f));
                }
                v = fmaxf(v, __shfl_xor(v, 1));
                v = fmaxf(v, __shfl_xor(v, 2));
                v = fmaxf(v, __shfl_xor(v, 4));
                v = fmaxf(v, __shfl_xor(v, 8));
                if (c == 0 && co < Co)
                    atomicMax((int*)&pool_out[(size_t)b * 1420 + pool_coloff + co],
                              __float_as_int(v));
            }
        }
    } else {
        #pragma unroll
        for (int i = 0; i < 4; ++i) {
            #pragma unroll
            for (int r = 0; r < 4; ++r) {
                int co = co0 + i * 16 + q * 4 + r;
                if (co >= Co) continue;
                float bv = bias[co];
                #pragma unroll
                for (int j = 0; j < 4; ++j) {
                    int t = t0 + w * 64 + j * 16 + c;
                    if (t < Lout) {
                        yout[((size_t)b * Co + co) * LoutPad + t] =
                            f2bf(fmaxf(acc[i][j][r] + bv, 0.f));
                    } else if (t < LoutPad) {
                        yout[((size_t)b * Co + co) * LoutPad + t] = 0;
                    }
                }
            }
        }
    }
}

// conv1 with fused embedding lookup (V <= 71). KP=8, Ci=64, ITILE=4.
__device__ __forceinline__ void conv1e_body(const int* __restrict__ toks,
                                            const float* __restrict__ table, int V, int L,
                                            const unsigned short* __restrict__ Wt, int KK,
                                            const float* __restrict__ bias, int Co,
                                            unsigned short* __restrict__ yout,
                                            int Lout, int LoutPad,
                                            int b, int co0, int t0,
                                            unsigned short* As, unsigned short* xraw,
                                            unsigned short* tabT, int* tok_s) {
    const int tid = threadIdx.x;
    const int lane = tid & 63, w = tid >> 6, c = lane & 15, q = lane >> 4;
    for (int idx = tid; idx < 64 * V; idx += 256) {
        int ci = idx / V, v = idx % V;
        tabT[ci * 72 + v] = f2bf(table[(size_t)v * 64 + ci]);
    }
    for (int t = tid; t < 272; t += 256) {
        int gt = t0 + t;
        tok_s[t] = (gt < L) ? toks[(size_t)b * L + gt] : 0;
    }
    __syncthreads();
    f32x4 acc[4][4];
    #pragma unroll
    for (int i = 0; i < 4; ++i)
        #pragma unroll
        for (int j = 0; j < 4; ++j) acc[i][j] = (f32x4){0.f, 0.f, 0.f, 0.f};
    const int row8 = tid >> 3, col8 = (tid & 7) * 8;
    for (int ch = 0; ch < 8; ++ch) {
        const int kkbase = ch * 64, ci0 = ch * 8;
        #pragma unroll
        for (int p = 0; p < 2; ++p) {
            int row = row8 + p * 32;
            *(uint4*)&As[row * 72 + col8] =
                *(const uint4*)&Wt[(size_t)(co0 + row) * KK + kkbase + col8];
        }
        for (int gi = tid; gi < 8 * 272; gi += 256) {
            int ci = gi / 272, t = gi % 272;
            xraw[gi] = tabT[(ci0 + ci) * 72 + tok_s[t]];
        }
        __syncthreads();
        #pragma unroll
        for (int ks = 0; ks < 2; ++ks) {
            const int kc = ks * 32;
            FragU af[4];
            #pragma unroll
            for (int i = 0; i < 4; ++i)
                af[i].q = *(const uint4*)&As[(i * 16 + c) * 72 + kc + q * 8];
            const int koff = kc + q * 8;
            const int cioff = koff >> 3;
            const uint32_t* xr = (const uint32_t*)xraw + cioff * 136;
            #pragma unroll
            for (int j = 0; j < 4; ++j) {
                int tt = w * 64 + j * 16 + c;
                int d0 = tt >> 1;
                unsigned sh = (unsigned)(tt & 1) * 16u;
                uint32_t u0 = xr[d0], u1 = xr[d0 + 1], u2 = xr[d0 + 2],
                         u3 = xr[d0 + 3], u4 = xr[d0 + 4];
                FragU bf;
                bf.u[0] = __builtin_amdgcn_alignbit(u1, u0, sh);
                bf.u[1] = __builtin_amdgcn_alignbit(u2, u1, sh);
                bf.u[2] = __builtin_amdgcn_alignbit(u3, u2, sh);
                bf.u[3] = __builtin_amdgcn_alignbit(u4, u3, sh);
                #pragma unroll
                for (int i = 0; i < 4; ++i)
                    acc[i][j] = __builtin_amdgcn_mfma_f32_16x16x32_bf16(af[i].s, bf.s,
                                                                        acc[i][j], 0, 0, 0);
            }
        }
        __syncthreads();
    }
    #pragma unroll
    for (int i = 0; i < 4; ++i) {
        #pragma unroll
        for (int r = 0; r < 4; ++r) {
            int co = co0 + i * 16 + q * 4 + r;
            if (co >= Co) continue;
            float bv = bias[co];
            #pragma unroll
            for (int j = 0; j < 4; ++j) {
                int t = t0 + w * 64 + j * 16 + c;
                if (t < Lout) {
                    yout[((size_t)b * Co + co) * LoutPad + t] =
                        f2bf(fmaxf(acc[i][j][r] + bv, 0.f));
                } else if (t < LoutPad) {
                    yout[((size_t)b * Co + co) * LoutPad + t] = 0;
                }
            }
        }
    }
}

// ---------------------------------------------------------------------------
// merged kernels, 1-D grid: ids [0,nconv) = conv part, [nconv,..) = rider part.
// m1: conv1 (320 blocks: 256 protein + 64 drug) + gnn_front (128 blocks)
__global__ __launch_bounds__(256) void m1_k(int nconv,
    const int* ptoks, const float* ptable, const unsigned short* WtP1,
    const float* pb1, unsigned short* y1p,
    const int* dtoks, const float* dtable, const unsigned short* WtD1,
    const float* db1, unsigned short* y1d,
    const int* ddi, const int* ppi, const int* dpi,
    const int* dntoks, const int* pntoks,
    const float* dntable, const float* pntable,
    float* RHO, unsigned short* Ad, unsigned short* Ap) {
    __shared__ __align__(16) char pool[29568];
    int id = blockIdx.x;
    if (id < nconv) {
        unsigned short* As = (unsigned short*)pool;
        unsigned short* xraw = (unsigned short*)(pool + 9216);
        unsigned short* tabT = (unsigned short*)(pool + 13568);
        int* tok_s = (int*)(pool + 22784);
        if (id < 256) {
            conv1e_body(ptoks, ptable, 26, 1000, WtP1, 512, pb1, 40, y1p, 997, 1000,
                        id >> 2, 0, (id & 3) * 256, As, xraw, tabT, tok_s);
        } else {
            conv1e_body(dtoks, dtable, 71, 100, WtD1, 512, db1, 40, y1d, 97, 104,
                        id - 256, 0, 0, As, xraw, tabT, tok_s);
        }
    } else {
        int t = id - nconv;
        gnn_front_body(ddi, ppi, dpi, dntoks, pntoks, dntable, pntable,
                       RHO, Ad, Ap, t >> 6, t & 63, pool);
    }
}

// m2: conv2 (640: 512 protein + 128 drug) + sk_stage1 (768 blocks)
__global__ __launch_bounds__(256) void m2_k(int nconv,
    const unsigned short* y1p, const unsigned short* WtP2, const float* pb2,
    unsigned short* y2p,
    const unsigned short* y1d, const unsigned short* WtD2, const float* db2,
    unsigned short* y2d,
    const unsigned short* Ad, const unsigned short* WdS, float* Ud,
    const unsigned short* Ap, const unsigned short* WpS, float* Up) {
    __shared__ __align__(16) char pool[13568];
    int id = blockIdx.x;
    if (id < nconv) {
        unsigned short* As = (unsigned short*)pool;
        unsigned short* xraw = (unsigned short*)(pool + 9216);
        if (id < 512) {
            conv_body<8>(y1p, 40, 1000, WtP2, 320, 5, pb2, 80, y2p, 990, 992,
                         nullptr, 0, id >> 3, ((id >> 2) & 1) * 64, (id & 3) * 256, As, xraw);
        } else {
            int t = id - 512;
            conv_body<8>(y1d, 40, 104, WtD2, 320, 5, db2, 80, y2d, 92, 96,
                         nullptr, 0, t >> 1, (t & 1) * 64, 0, As, xraw);
        }
    } else {
        int t = id - nconv;
        int bx = t & 15, by = (t >> 4) & 7, bz = t >> 7;
        if (bz < 3) {
            sk_body(Ap, 2208, WpS, 2208, 2208, 8, 0.5f, Up, 1024, 0, 1000, bx, by, bz);
        } else {
            if (bx >= 2) return;
            sk_body(Ad, 1248, WdS, 1248, 1248, 8, 0.5f, Ud, 112, 0, 100, bx, by, bz - 3);
        }
    }
}

// m3: conv3 (960: 768 protein + 192 drug) + ep (852 blocks)
__global__ __launch_bounds__(256) void m3_k(int nconv,
    const unsigned short* y2p, const unsigned short* WtP3, const float* pb3,
    float* pair,
    const unsigned short* y2d, const unsigned short* WtD3, const float* db3,
    const float* Ud, const float* Up, const float* RHO,
    const float* bd, const float* bp,
    unsigned short* A2d, unsigned short* A2p) {
    __shared__ __align__(16) char pool[13568];
    int id = blockIdx.x;
    if (id < nconv) {
        unsigned short* As = (unsigned short*)pool;
        unsigned short* xraw = (unsigned short*)(pool + 9216);
        if (id < 768) {
            int z = id / 12, r = id % 12;
            conv_body<16>(y2p, 80, 992, WtP3, 1280, 20, pb3, 160, nullptr, 979, 0,
                          pair, 160, z, (r >> 2) * 64, (r & 3) * 256, As, xraw);
        } else {
            int t = id - 768;
            conv_body<8>(y2d, 80, 96, WtD3, 640, 10, db3, 160, nullptr, 85, 0,
                         pair, 0, t / 3, (t % 3) * 64, 0, As, xraw);
        }
    } else {
        int idx = (id - nconv) * 256 + threadIdx.x;
        ep_item(idx, Ud, Up, RHO, bd, bp, A2d, A2p);
    }
}

// stage-2 skinny GEMM: z==0 protein -> pair[420:], z==1 drug (x<2). grid (16,8,2)
__global__ __launch_bounds__(256) void sk_stage2(const unsigned short* __restrict__ A2d,
                                                 const unsigned short* __restrict__ WdS,
                                                 const unsigned short* __restrict__ A2p,
                                                 const unsigned short* __restrict__ WpS,
                                                 float* __restrict__ pair) {
    int z = blockIdx.z;
    if (z == 0) {
        sk_body(A2p, 2208, WpS, 2208, 2208, 8, 0.5f, pair, 1420, 420, 1000,
                blockIdx.x, blockIdx.y, 0);
    } else {
        if (blockIdx.x >= 2) return;
        sk_body(A2d, 1248, WdS, 1248, 1248, 8, 0.5f, pair, 1420, 320, 100,
                blockIdx.x, blockIdx.y, 0);
    }
}

// ---------------------------------------------------------------------------
// fp32 NT-SGEMM (FC head), split-K atomic; optional leaky(bias) applied to A.
__global__ __launch_bounds__(256) void gemm_nt(const float* __restrict__ A, int lda,
                                               const float* __restrict__ Aep_b,
                                               const float* __restrict__ Bm,
                                               float* __restrict__ Cout,
                                               int M, int N, int K, int KC) {
    const int m0 = blockIdx.x * 64, n0 = blockIdx.y * 64, s = blockIdx.z;
    const int tid = threadIdx.x, ty = tid >> 4, tx = tid & 15;
    __shared__ __align__(16) float As[16][68];
    __shared__ __align__(16) float Bs[16][68];
    float acc[4][4] = {};
    const int kbeg = s * KC, kend = min(K, kbeg + KC);
    for (int k0 = kbeg; k0 < kend; k0 += 16) {
        int colk = k0 + tx;
        bool kok = colk < kend;
        #pragma unroll
        for (int qq = 0; qq < 4; ++qq) {
            int mi = ty + qq * 16;
            float va = 0.f;
            if (kok && (m0 + mi) < M) {
                va = A[(size_t)(m0 + mi) * lda + colk];
                if (Aep_b) {
                    va += Aep_b[colk];
                    va = va >= 0.f ? va : 0.01f * va;
                }
            }
            As[tx][mi] = va;
            Bs[tx][mi] = (kok && (n0 + mi) < N) ? Bm[(size_t)(n0 + mi) * K + colk] : 0.f;
        }
        __syncthreads();
        #pragma unroll
        for (int kk = 0; kk < 16; ++kk) {
            float4 a4 = *(const float4*)&As[kk][ty * 4];
            float4 b4 = *(const float4*)&Bs[kk][tx * 4];
            float av[4] = {a4.x, a4.y, a4.z, a4.w};
            float bv[4] = {b4.x, b4.y, b4.z, b4.w};
            #pragma unroll
            for (int i = 0; i < 4; ++i)
                #pragma unroll
                for (int j = 0; j < 4; ++j)
                    acc[i][j] = fmaf(av[i], bv[j], acc[i][j]);
        }
        __syncthreads();
    }
    #pragma unroll
    for (int i = 0; i < 4; ++i) {
        int m = m0 + ty * 4 + i;
        if (m >= M) continue;
        #pragma unroll
        for (int j = 0; j < 4; ++j) {
            int n = n0 + tx * 4 + j;
            if (n >= N) continue;
            atomicAdd(&Cout[(size_t)m * N + n], acc[i][j]);
        }
    }
}

__global__ void out_k(const float* __restrict__ cf3, const float* __restrict__ b3,
                      const float* __restrict__ W, const float* __restrict__ bias,
                      float* __restrict__ out) {
    int tid = threadIdx.x;
    if (tid >= 128) return;
    int b = tid >> 1, n = tid & 1;
    const float* hr = cf3 + (size_t)b * 512;
    const float* wr = W + (size_t)n * 512;
    float a = 0.f;
    for (int k = 0; k < 512; ++k) {
        float v = hr[k] + b3[k];
        v = v >= 0.f ? v : 0.01f * v;
        a = fmaf(v, wr[k], a);
    }
    out[b * 2 + n] = a + bias[n];
}

// ---------------------------------------------------------------------------
static inline int kc_of(int K, int S) { return ((K + S * 16 - 1) / (S * 16)) * 16; }
static inline dim3 g1d(int n) { return dim3((n + 255) / 256); }

extern "C" void kernel_launch(void* const* d_in, const int* in_sizes, int n_in,
                              void* d_out, int out_size, void* d_ws, size_t ws_size,
                              hipStream_t stream) {
    const int* drug_tokens       = (const int*)d_in[0];
    const int* protein_tokens    = (const int*)d_in[1];
    const int* drug_node_tokens  = (const int*)d_in[2];
    const int* protein_node_toks = (const int*)d_in[3];
    const int* ddi_edges         = (const int*)d_in[4];
    const int* ppi_edges         = (const int*)d_in[5];
    const int* dpi_edges         = (const int*)d_in[6];
    const float* drug_embed      = (const float*)d_in[7];
    const float* protein_embed   = (const float*)d_in[8];
    const float* dW1 = (const float*)d_in[9];  const float* db1 = (const float*)d_in[10];
    const float* dW2 = (const float*)d_in[11]; const float* db2 = (const float*)d_in[12];
    const float* dW3 = (const float*)d_in[13]; const float* db3 = (const float*)d_in[14];
    const float* pW1 = (const float*)d_in[15]; const float* pb1 = (const float*)d_in[16];
    const float* pW2 = (const float*)d_in[17]; const float* pb2 = (const float*)d_in[18];
    const float* pW3 = (const float*)d_in[19]; const float* pb3 = (const float*)d_in[20];
    const float* drug_node_table = (const float*)d_in[21];
    const float* prot_node_table = (const float*)d_in[22];
    const float* ddi_Wl = (const float*)d_in[23]; const float* ddi_bl = (const float*)d_in[24];
    const float* ddi_Wr = (const float*)d_in[25];
    const float* ppi_Wl = (const float*)d_in[26]; const float* ppi_bl = (const float*)d_in[27];
    const float* ppi_Wr = (const float*)d_in[28];
    const float* dpi_Wl = (const float*)d_in[29]; const float* dpi_bl = (const float*)d_in[30];
    const float* dpi_Wr = (const float*)d_in[31];
    const float* pdi_Wl = (const float*)d_in[32]; const float* pdi_bl = (const float*)d_in[33];
    const float* pdi_Wr = (const float*)d_in[34];
    const float* fc1_W = (const float*)d_in[35]; const float* fc1_b = (const float*)d_in[36];
    const float* fc2_W = (const float*)d_in[37]; const float* fc2_b = (const float*)d_in[38];
    const float* fc3_W = (const float*)d_in[39]; const float* fc3_b = (const float*)d_in[40];
    const float* out_W = (const float*)d_in[41]; const float* out_b = (const float*)d_in[42];

    float* outp = (float*)d_out;
    if (ws_size < NEED_FB) {
        zero32_k<<<g1d(out_size), 256, 0, stream>>>((uint32_t*)outp, out_size);
        return;
    }
    const bool full = (ws_size >= NEED_FULL);

    char* wsb = (char*)d_ws;
    float* pair = (float*)(wsb + O_PAIR);
    float* cf1 = (float*)(wsb + O_CF1); float* cf2 = (float*)(wsb + O_CF2);
    float* cf3 = (float*)(wsb + O_CF3);
    float* bd = (float*)(wsb + O_BD); float* bp = (float*)(wsb + O_BP);
    unsigned short* WdS  = (unsigned short*)(wsb + O_WDS);
    unsigned short* WpS  = (unsigned short*)(wsb + O_WPS);
    unsigned short* WtP1 = (unsigned short*)(wsb + O_WTP1);
    unsigned short* WtP2 = (unsigned short*)(wsb + O_WTP2);
    unsigned short* WtP3 = (unsigned short*)(wsb + O_WTP3);
    unsigned short* WtD1 = (unsigned short*)(wsb + O_WTD1);
    unsigned short* WtD2 = (unsigned short*)(wsb + O_WTD2);
    unsigned short* WtD3 = (unsigned short*)(wsb + O_WTD3);
    unsigned short* Ad  = (unsigned short*)(wsb + A_AD);
    unsigned short* Ap  = (unsigned short*)(wsb + A_AP);
    unsigned short* A2d = (unsigned short*)(wsb + A_A2D);
    unsigned short* A2p = (unsigned short*)(wsb + A_A2P);
    float* Ud  = (float*)(wsb + A_UD);
    float* Up  = (float*)(wsb + A_UP);
    float* RHO = (float*)(wsb + A_RHO);
    // conv buffers: overlapped layout after GNN region if ws permits, else R8 alias.
    size_t cbase = full ? GNN_END : AR;
    unsigned short* y2p = (unsigned short*)(wsb + cbase);
    unsigned short* y1p = (unsigned short*)(wsb + cbase + SZ_Y2P);
    unsigned short* y1d = (unsigned short*)(wsb + cbase + SZ_Y2P + SZ_Y1P);
    unsigned short* y2d = (unsigned short*)(wsb + cbase + SZ_Y2P + SZ_Y1P + SZ_Y1D);

    // 1) prep: weights + biases + pair biasfill/zero + cf zero + GNN zero
    prep_k<<<g1d((int)Q17), 256, 0, stream>>>(bd, bp, WdS, WpS,
                                              WtP1, WtP2, WtP3, WtD1, WtD2, WtD3,
                                              pair, cf1, (uint32_t*)(wsb + A_AD),
                                              ddi_Wl, ddi_bl, ddi_Wr,
                                              ppi_Wl, ppi_bl, ppi_Wr,
                                              dpi_Wl, dpi_bl, dpi_Wr,
                                              pdi_Wl, pdi_bl, pdi_Wr,
                                              dW1, dW2, dW3, pW1, pW2, pW3);

    if (full) {
        // overlapped schedule: GNN chain rides inside conv launches
        m1_k<<<dim3(320 + 128), 256, 0, stream>>>(320,
            protein_tokens, protein_embed, WtP1, pb1, y1p,
            drug_tokens, drug_embed, WtD1, db1, y1d,
            ddi_edges, ppi_edges, dpi_edges, drug_node_tokens, protein_node_toks,
            drug_node_table, prot_node_table, RHO, Ad, Ap);
        m2_k<<<dim3(640 + 768), 256, 0, stream>>>(640,
            y1p, WtP2, pb2, y2p, y1d, WtD2, db2, y2d,
            Ad, WdS, Ud, Ap, WpS, Up);
        m3_k<<<dim3(960 + 852), 256, 0, stream>>>(960,
            y2p, WtP3, pb3, pair, y2d, WtD3, db3,
            Ud, Up, RHO, bd, bp, A2d, A2p);
        sk_stage2<<<dim3(16, 8, 2), 256, 0, stream>>>(A2d, WdS, A2p, WpS, pair);
    } else {
        // R8 serial schedule (conv buffers alias dead GNN region)
        m1_k<<<dim3(128), 256, 0, stream>>>(0,
            protein_tokens, protein_embed, WtP1, pb1, y1p,
            drug_tokens, drug_embed, WtD1, db1, y1d,
            ddi_edges, ppi_edges, dpi_edges, drug_node_tokens, protein_node_toks,
            drug_node_table, prot_node_table, RHO, Ad, Ap);
        m2_k<<<dim3(768), 256, 0, stream>>>(0,
            y1p, WtP2, pb2, y2p, y1d, WtD2, db2, y2d,
            Ad, WdS, Ud, Ap, WpS, Up);
        m3_k<<<dim3(852), 256, 0, stream>>>(0,
            y2p, WtP3, pb3, pair, y2d, WtD3, db3,
            Ud, Up, RHO, bd, bp, A2d, A2p);
        sk_stage2<<<dim3(16, 8, 2), 256, 0, stream>>>(A2d, WdS, A2p, WpS, pair);
        m1_k<<<dim3(320), 256, 0, stream>>>(320,
            protein_tokens, protein_embed, WtP1, pb1, y1p,
            drug_tokens, drug_embed, WtD1, db1, y1d,
            ddi_edges, ppi_edges, dpi_edges, drug_node_tokens, protein_node_toks,
            drug_node_table, prot_node_table, RHO, Ad, Ap);
        m2_k<<<dim3(640), 256, 0, stream>>>(640,
            y1p, WtP2, pb2, y2p, y1d, WtD2, db2, y2d,
            Ad, WdS, Ud, Ap, WpS, Up);
        m3_k<<<dim3(960), 256, 0, stream>>>(960,
            y2p, WtP3, pb3, pair, y2d, WtD3, db3,
            Ud, Up, RHO, bd, bp, A2d, A2p);
    }

    // FC head (fp32, split-K 16; leaky+bias fused into next gemm's A-load)
    gemm_nt<<<dim3(1, 16, 16), 256, 0, stream>>>(pair, 1420, nullptr, fc1_W, cf1,
                                                 64, 1024, 1420, kc_of(1420, 16));
    gemm_nt<<<dim3(1, 16, 16), 256, 0, stream>>>(cf1, 1024, fc1_b, fc2_W, cf2,
                                                 64, 1024, 1024, kc_of(1024, 16));
    gemm_nt<<<dim3(1, 8, 16), 256, 0, stream>>>(cf2, 1024, fc2_b, fc3_W, cf3,
                                                64, 512, 1024, kc_of(1024, 16));
    out_k<<<dim3(1), 128, 0, stream>>>(cf3, fc3_b, out_W, out_b, outp);
}

// Round 11
// 441.811 us; speedup vs baseline: 1.1282x; 1.0556x over previous
//
#include <hip/hip_runtime.h>
#include <hip/hip_bf16.h>

// ---------------------------------------------------------------------------
// SSGraphDTI forward. bf16 MFMA convs + collapsed-affine GNN, fp32 FC head.
// R11: JT=2 conv tiles (t-tile 128, 2x blocks, same amortization, lower VGPR);
// lean co-dispatch only (sk1 rides conv2, ep rides conv3; gnn_front & conv1
// standalone — R10 showed fat unions poison occupancy). Full non-aliased
// layout (26.33MB, confirmed fits) w/ R8-serial fallback. 10 launches.
// ---------------------------------------------------------------------------

typedef __attribute__((ext_vector_type(8))) short short8;
typedef __attribute__((ext_vector_type(4))) float f32x4;
union FragU { uint32_t u[4]; uint4 q; short8 s; };

static __device__ inline unsigned short f2bf(float v) {
    __hip_bfloat16 h = __float2bfloat16(v);
    return *(unsigned short*)&h;
}

// ---------------- workspace layout (byte offsets) ----------------
static constexpr size_t O_PAIR = 0;            // 64*1420 f32
static constexpr size_t O_CF1  = 363520;       // 64*1024 f32
static constexpr size_t O_CF2  = 625664;       // 64*1024 f32
static constexpr size_t O_CF3  = 887808;       // 64*512 f32 -> 1,018,880
static constexpr size_t O_BD   = 1018880;      // 128 f32
static constexpr size_t O_BP   = 1019392;      // 1024 f32
static constexpr size_t O_WDS  = 1023488;      // 128x1248 bf16
static constexpr size_t O_WPS  = 1342976;      // 1024x2208 bf16
static constexpr size_t O_WTP1 = 5864960;      // 64x512 bf16
static constexpr size_t O_WTP2 = 5930496;      // 128x320 bf16
static constexpr size_t O_WTP3 = 6012416;      // 192x1280 bf16
static constexpr size_t O_WTD1 = 6503936;      // 64x512 bf16
static constexpr size_t O_WTD2 = 6569472;      // 128x320 bf16
static constexpr size_t O_WTD3 = 6651392;      // 192x640 bf16
static constexpr size_t AR     = 6897152;      // aliased region base
// GNN region:
static constexpr size_t A_AD  = AR + 0;        // 192x1248 bf16
static constexpr size_t A_AP  = AR + 479232;   // 192x2208 bf16
static constexpr size_t A_A2D = AR + 1327104;  // 64x1248 bf16
static constexpr size_t A_A2P = AR + 1486848;  // 64x2208 bf16
static constexpr size_t A_UD  = AR + 1769472;  // 192x112 f32
static constexpr size_t A_UP  = AR + 1855488;  // 192x1024 f32
static constexpr size_t A_RHO = AR + 2641920;  // 64x4 f32
static constexpr size_t GNN_END = AR + 2642944;
// conv sizes:
static constexpr size_t SZ_Y2P = 10158080;     // 64x80x992 bf16
static constexpr size_t SZ_Y1P = 5120000;      // 64x40x1000 bf16
static constexpr size_t SZ_Y1D = 532480;       // 64x40x104 bf16
static constexpr size_t SZ_Y2D = 983040;       // 64x80x96 bf16
static constexpr size_t NEED_FB   = AR + SZ_Y2P + SZ_Y1P + SZ_Y1D + SZ_Y2D;      // 23.69MB
static constexpr size_t NEED_FULL = GNN_END + SZ_Y2P + SZ_Y1P + SZ_Y1D + SZ_Y2D; // 26.33MB (confirmed fits)

// ---------------------------------------------------------------------------
__global__ void zero32_k(uint32_t* __restrict__ p, int n) {
    int i = blockIdx.x * 256 + threadIdx.x;
    if (i < n) p[i] = 0u;
}

// ---------------- fused prep (R8-identical) ----------------
static constexpr long Q0 = 100;
static constexpr long Q1 = Q0 + 1000;
static constexpr long Q2 = Q1 + 14336;
static constexpr long Q3 = Q2 + 14336;
static constexpr long Q4 = Q3 + 131072;
static constexpr long Q5 = Q4 + 1048576;
static constexpr long Q6 = Q5 + 1048576;
static constexpr long Q7 = Q6 + 163840;
static constexpr long Q8 = Q7 + 32768;
static constexpr long Q9 = Q8 + 40960;
static constexpr long Q10 = Q9 + 245760;
static constexpr long Q11 = Q10 + 32768;
static constexpr long Q12 = Q11 + 40960;
static constexpr long Q13 = Q12 + 122880;
static constexpr long Q14 = Q13 + 70400;
static constexpr long Q15 = Q14 + 20480;
static constexpr long Q16 = Q15 + 163840;
static constexpr long Q17 = Q16 + 660736;

__device__ inline void wt_block(unsigned short* dst, int ld_dst, int coloff,
                                const float* s1, const float* s2, int ld_src,
                                int N, int Kreal, int Kblk, long local) {
    int n = (int)(local / Kblk), k = (int)(local % Kblk);
    float v = 0.f;
    if (n < N && k < Kreal) {
        v = s1[(size_t)n * ld_src + k];
        if (s2) v += s2[(size_t)n * ld_src + k];
    }
    dst[(size_t)n * ld_dst + coloff + k] = f2bf(v);
}

__device__ inline void wtconv_block(unsigned short* dst, const float* W,
                                    int Co, int Ci, int K, int KP, long local) {
    int co = (int)(local / (Ci * KP));
    int rem = (int)(local % (Ci * KP));
    int ci = rem / KP, k = rem % KP;
    float v = (co < Co && k < K) ? W[((size_t)co * Ci + ci) * K + k] : 0.f;
    dst[local] = f2bf(v);
}

__global__ __launch_bounds__(256) void prep_k(
    float* bd, float* bp, unsigned short* WdS, unsigned short* WpS,
    unsigned short* WtP1, unsigned short* WtP2, unsigned short* WtP3,
    unsigned short* WtD1, unsigned short* WtD2, unsigned short* WtD3,
    float* pair, float* cfz, uint32_t* gnnz,
    const float* ddi_Wl, const float* ddi_bl, const float* ddi_Wr,
    const float* ppi_Wl, const float* ppi_bl, const float* ppi_Wr,
    const float* dpi_Wl, const float* dpi_bl, const float* dpi_Wr,
    const float* pdi_Wl, const float* pdi_bl, const float* pdi_Wr,
    const float* dW1, const float* dW2, const float* dW3,
    const float* pW1, const float* pW2, const float* pW3) {
    long idx = (long)blockIdx.x * 256 + threadIdx.x;
    if (idx < Q0) { bd[idx] = 0.5f * (ddi_bl[idx] + pdi_bl[idx]); return; }
    if (idx < Q1) { long j = idx - Q0; bp[j] = 0.5f * (ppi_bl[j] + dpi_bl[j]); return; }
    if (idx < Q2) { wt_block(WdS, 1248, 0, ddi_Wl, nullptr, 100, 100, 100, 112, idx - Q1); return; }
    if (idx < Q3) { wt_block(WdS, 1248, 112, ddi_Wr, pdi_Wr, 100, 100, 100, 112, idx - Q2); return; }
    if (idx < Q4) { wt_block(WdS, 1248, 224, pdi_Wl, nullptr, 1000, 100, 1000, 1024, idx - Q3); return; }
    if (idx < Q5) { wt_block(WpS, 2208, 0, ppi_Wl, nullptr, 1000, 1000, 1000, 1024, idx - Q4); return; }
    if (idx < Q6) { wt_block(WpS, 2208, 1024, ppi_Wr, dpi_Wr, 1000, 1000, 1000, 1024, idx - Q5); return; }
    if (idx < Q7) { wt_block(WpS, 2208, 2048, dpi_Wl, nullptr, 100, 1000, 100, 160, idx - Q6); return; }
    if (idx < Q8)  { wtconv_block(WtP1, pW1, 40, 64, 4, 8, idx - Q7); return; }
    if (idx < Q9)  { wtconv_block(WtP2, pW2, 80, 40, 8, 8, idx - Q8); return; }
    if (idx < Q10) { wtconv_block(WtP3, pW3, 160, 80, 12, 16, idx - Q9); return; }
    if (idx < Q11) { wtconv_block(WtD1, dW1, 40, 64, 4, 8, idx - Q10); return; }
    if (idx < Q12) { wtconv_block(WtD2, dW2, 80, 40, 6, 8, idx - Q11); return; }
    if (idx < Q13) { wtconv_block(WtD3, dW3, 160, 80, 8, 8, idx - Q12); return; }
    if (idx < Q14) {
        long l = idx - Q13;
        int b = (int)(l / 1100), j = (int)(l % 1100);
        if (j < 100) pair[(size_t)b * 1420 + 320 + j] = 0.5f * (ddi_bl[j] + pdi_bl[j]);
        else { int j2 = j - 100; pair[(size_t)b * 1420 + 420 + j2] = 0.5f * (ppi_bl[j2] + dpi_bl[j2]); }
        return;
    }
    if (idx < Q15) {
        long l = idx - Q14;
        int b = (int)(l / 320), j = (int)(l % 320);
        pair[(size_t)b * 1420 + j] = 0.f;
        return;
    }
    if (idx < Q16) { cfz[idx - Q15] = 0.f; return; }
    if (idx < Q17) { gnnz[idx - Q16] = 0u; return; }
}

// ---------------------------------------------------------------------------
// GNN front-end (standalone, R8-identical).
__global__ __launch_bounds__(256) void gnn_front_k(const int* __restrict__ ddi,
                                                   const int* __restrict__ ppi,
                                                   const int* __restrict__ dpi,
                                                   const int* __restrict__ dtoks,
                                                   const int* __restrict__ ptoks,
                                                   const float* __restrict__ dtable,
                                                   const float* __restrict__ ptable,
                                                   float* __restrict__ RHO,
                                                   unsigned short* __restrict__ Ad,
                                                   unsigned short* __restrict__ Ap) {
    const int role = blockIdx.x, b = blockIdx.y, tid = threadIdx.x;
    __shared__ float M[4][32][32];
    __shared__ int cnt4[4][32];
    __shared__ float inv4[4][32];
    __shared__ float W7[7][32];
    __shared__ int cnt[32][72];
    __shared__ float WC[7][72];
    for (int i = tid; i < 4 * 32 * 32; i += 256) ((float*)M)[i] = 0.f;
    if (tid < 128) ((int*)cnt4)[tid] = 0;
    __syncthreads();
    const int* ed = ddi + (size_t)b * 256;
    const int* ep = ppi + (size_t)b * 256;
    const int* ex = dpi + (size_t)b * 128;
    if (tid < 128) {
        atomicAdd(&cnt4[0][ed[128 + tid]], 1);
        atomicAdd(&cnt4[1][ep[128 + tid]], 1);
    } else if (tid < 192) {
        int e = tid - 128;
        atomicAdd(&cnt4[2][ex[e]], 1);
        atomicAdd(&cnt4[3][ex[64 + e]], 1);
    }
    __syncthreads();
    if (tid < 128) {
        int which = tid >> 5, j = tid & 31;
        inv4[which][j] = 1.f / (float)max(cnt4[which][j], 1);
    }
    __syncthreads();
    if (tid < 128) {
        int s = ed[tid], d = ed[128 + tid];
        atomicAdd(&M[0][d][s], inv4[0][d]);
        int s2 = ep[tid], d2 = ep[128 + tid];
        atomicAdd(&M[1][d2][s2], inv4[1][d2]);
    } else if (tid < 192) {
        int e = tid - 128;
        int dr = ex[e], pr = ex[64 + e];
        atomicAdd(&M[2][dr][pr], inv4[2][dr]);
        atomicAdd(&M[3][pr][dr], inv4[3][pr]);
    }
    __syncthreads();
    if (tid < 32) {
        int j = tid;
        if (role == 0) {
            float r1 = 0.f, r4 = 0.f, r5 = 0.f, r7 = 0.f;
            for (int k = 0; k < 32; ++k) {
                r1 += M[0][0][k] * M[0][k][j];
                r4 += M[2][0][k] * M[3][k][j];
                r5 += M[1][0][k] * M[3][k][j];
                r7 += M[3][0][k] * M[0][k][j];
            }
            W7[0][j] = r1; W7[1][j] = M[0][0][j]; W7[2][j] = (j == 0) ? 1.f : 0.f;
            W7[3][j] = r4; W7[4][j] = r5; W7[5][j] = M[3][0][j]; W7[6][j] = r7;
        } else {
            float s1 = 0.f, s3 = 0.f, s4 = 0.f, s7 = 0.f;
            for (int k = 0; k < 32; ++k) {
                s1 += M[0][0][k] * M[2][k][j];
                s3 += M[2][0][k] * M[1][k][j];
                s4 += M[1][0][k] * M[1][k][j];
                s7 += M[3][0][k] * M[2][k][j];
            }
            W7[0][j] = s1; W7[1][j] = M[2][0][j]; W7[2][j] = s3;
            W7[3][j] = s4; W7[4][j] = M[1][0][j];
            W7[5][j] = (j == 0) ? 1.f : 0.f; W7[6][j] = s7;
        }
    }
    if (role == 0 && tid == 0) {
        float a = 0.f, bq = 0.f, cq = 0.f, dq = 0.f;
        for (int k = 0; k < 32; ++k) {
            a += M[0][0][k]; bq += M[2][0][k]; cq += M[1][0][k]; dq += M[3][0][k];
        }
        RHO[b * 4 + 0] = a; RHO[b * 4 + 1] = bq; RHO[b * 4 + 2] = cq; RHO[b * 4 + 3] = dq;
    }
    const int V = role ? 26 : 71;
    const int L = role ? 1000 : 100;
    for (int i = tid; i < 32 * 72; i += 256) ((int*)cnt)[i] = 0;
    __syncthreads();
    const int* tk = (role ? ptoks : dtoks) + (size_t)b * 32 * L;
    for (int i = tid; i < 32 * L; i += 256) atomicAdd(&cnt[i / L][tk[i]], 1);
    __syncthreads();
    float invL = 1.f / (float)L;
    for (int o = tid; o < 7 * V; o += 256) {
        int i = o / V, v = o % V;
        float a = 0.f;
        for (int k = 0; k < 32; ++k) a += W7[i][k] * (float)cnt[k][v];
        WC[i][v] = a * invL;
    }
    __syncthreads();
    size_t g0d = (size_t)b * 1248, g1d_ = (size_t)(64 + b) * 1248, g2d = (size_t)(128 + b) * 1248;
    size_t g0p = (size_t)b * 2208, g1p = (size_t)(64 + b) * 2208, g2p = (size_t)(128 + b) * 2208;
    if (role == 0) {
        int d = tid;
        if (d >= 100) return;
        float acc[7] = {};
        for (int v = 0; v < 71; ++v) {
            float tv = dtable[(size_t)v * 100 + d];
            #pragma unroll
            for (int i = 0; i < 7; ++i) acc[i] += WC[i][v] * tv;
        }
        unsigned short h;
        h = f2bf(acc[0]); Ad[g0d + d] = h;
        h = f2bf(acc[1]); Ad[g0d + 112 + d] = h; Ad[g1d_ + d] = h;
        h = f2bf(acc[2]); Ad[g1d_ + 112 + d] = h;
        h = f2bf(acc[3]); Ap[g0p + 2048 + d] = h;
        h = f2bf(acc[4]); Ap[g1p + 2048 + d] = h;
        h = f2bf(acc[5]); Ap[g2p + 2048 + d] = h; Ad[g2d + 112 + d] = h;
        h = f2bf(acc[6]); Ad[g2d + d] = h;
    } else {
        for (int d = tid; d < 1000; d += 256) {
            float acc[7] = {};
            for (int v = 0; v < 26; ++v) {
                float tv = ptable[(size_t)v * 1000 + d];
                #pragma unroll
                for (int i = 0; i < 7; ++i) acc[i] += WC[i][v] * tv;
            }
            unsigned short h;
            h = f2bf(acc[0]); Ad[g0d + 224 + d] = h;
            h = f2bf(acc[1]); Ad[g1d_ + 224 + d] = h; Ap[g0p + 1024 + d] = h;
            h = f2bf(acc[2]); Ap[g0p + d] = h;
            h = f2bf(acc[3]); Ap[g1p + d] = h;
            h = f2bf(acc[4]); Ap[g1p + 1024 + d] = h; Ap[g2p + d] = h;
            h = f2bf(acc[5]); Ap[g2p + 1024 + d] = h;
            h = f2bf(acc[6]); Ad[g2d + 224 + d] = h;
        }
    }
}

// ---------------------------------------------------------------------------
// skinny bf16 MFMA GEMM body (R8-identical)
__device__ __forceinline__ void sk_body(const unsigned short* __restrict__ A, int lda,
                                        const unsigned short* __restrict__ Bm, int ldb,
                                        int K, int KS, float scale,
                                        float* __restrict__ out,
                                        int rs, int coloff, int Nw,
                                        int bx, int by, int gz) {
    const int tid = threadIdx.x;
    const int lane = tid & 63, w = tid >> 6, c = lane & 15, q = lane >> 4;
    const int n = bx * 64 + w * 16 + c;
    const unsigned short* Ab = A + (size_t)gz * 64 * lda;
    const int Ks = ((K / KS + 31) / 32) * 32;
    const int k0 = by * Ks;
    const int k1 = min(K, k0 + Ks);
    f32x4 acc[4];
    #pragma unroll
    for (int i = 0; i < 4; ++i) acc[i] = (f32x4){0.f, 0.f, 0.f, 0.f};
    for (int k = k0; k < k1; k += 32) {
        FragU bf;
        bf.q = *(const uint4*)&Bm[(size_t)n * ldb + k + q * 8];
        #pragma unroll
        for (int i = 0; i < 4; ++i) {
            FragU af;
            af.q = *(const uint4*)&Ab[(size_t)(i * 16 + c) * lda + k + q * 8];
            acc[i] = __builtin_amdgcn_mfma_f32_16x16x32_bf16(af.s, bf.s, acc[i], 0, 0, 0);
        }
    }
    if (n >= Nw) return;
    #pragma unroll
    for (int i = 0; i < 4; ++i)
        #pragma unroll
        for (int r = 0; r < 4; ++r) {
            int m = gz * 64 + i * 16 + q * 4 + r;
            atomicAdd(&out[(size_t)m * rs + coloff + n], scale * acc[i][r]);
        }
}

// ep item (R10 version, verified)
__device__ void ep_item(int idx, const float* __restrict__ Ud, const float* __restrict__ Up,
                        const float* __restrict__ RHO,
                        const float* __restrict__ bd, const float* __restrict__ bp,
                        unsigned short* __restrict__ A2d, unsigned short* __restrict__ A2p) {
    if (idx < 192 * 112) {
        int m = idx / 112, n = idx % 112;
        if (n >= 100) return;
        int g = m >> 6, b = m & 63;
        float rho = (g == 0) ? RHO[b * 4 + 0] : (g == 1) ? 1.f : RHO[b * 4 + 3];
        unsigned short h = f2bf(Ud[idx] + rho * bd[n]);
        if (g == 0) A2d[(size_t)b * 1248 + n] = h;
        else if (g == 1) A2d[(size_t)b * 1248 + 112 + n] = h;
        else A2p[(size_t)b * 2208 + 2048 + n] = h;
    } else {
        int l = idx - 192 * 112;
        if (l >= 192 * 1024) return;
        int m = l / 1024, n = l % 1024;
        if (n >= 1000) return;
        int g = m >> 6, b = m & 63;
        float rho = (g == 0) ? RHO[b * 4 + 1] : (g == 1) ? RHO[b * 4 + 2] : 1.f;
        unsigned short h = f2bf(Up[l] + rho * bp[n]);
        if (g == 0) A2d[(size_t)b * 1248 + 224 + n] = h;
        else if (g == 1) A2p[(size_t)b * 2208 + n] = h;
        else A2p[(size_t)b * 2208 + 1024 + n] = h;
    }
}

// ---------------------------------------------------------------------------
// conv1d implicit-GEMM bf16 MFMA body, ITILE=4, JT t-subtiles of 16 per wave
// (t-tile = JT*64). Single-buffer LDS (R8-proven). Per-output math identical
// to R8 regardless of JT.
template <int KP, int JT>
__device__ __forceinline__ void conv_body(const unsigned short* __restrict__ xin,
                                          int Ci, int Lp,
                                          const unsigned short* __restrict__ Wt, int KK,
                                          int nchunk,
                                          const float* __restrict__ bias, int Co,
                                          unsigned short* __restrict__ yout,
                                          int Lout, int LoutPad,
                                          float* __restrict__ pool_out, int pool_coloff,
                                          int b, int co0, int t0,
                                          unsigned short* As, unsigned short* xraw) {
    constexpr int CIPC = 64 / KP;
    constexpr int LG = (KP == 8) ? 3 : 4;
    constexpr int WROW = JT * 64 + 16;     // shorts per staged ci row
    constexpr int NU4 = WROW / 8;          // uint4 per row
    const int tid = threadIdx.x;
    const int lane = tid & 63, w = tid >> 6, c = lane & 15, q = lane >> 4;
    f32x4 acc[4][JT];
    #pragma unroll
    for (int i = 0; i < 4; ++i)
        #pragma unroll
        for (int j = 0; j < JT; ++j) acc[i][j] = (f32x4){0.f, 0.f, 0.f, 0.f};
    const int row8 = tid >> 3, col8 = (tid & 7) * 8;
    for (int ch = 0; ch < nchunk; ++ch) {
        const int kkbase = ch * 64, ci0 = ch * CIPC;
        #pragma unroll
        for (int p = 0; p < 2; ++p) {
            int row = row8 + p * 32;
            *(uint4*)&As[row * 72 + col8] =
                *(const uint4*)&Wt[(size_t)(co0 + row) * KK + kkbase + col8];
        }
        for (int gi = tid; gi < CIPC * NU4; gi += 256) {
            int ci = gi / NU4, g8 = (gi % NU4) * 8, gt = t0 + g8;
            const unsigned short* src = xin + ((size_t)b * Ci + ci0 + ci) * Lp + gt;
            if (gt + 8 <= Lp) {
                *(uint4*)&xraw[ci * WROW + g8] = *(const uint4*)src;
            } else {
                #pragma unroll
                for (int jj = 0; jj < 8; ++jj)
                    xraw[ci * WROW + g8 + jj] = (gt + jj < Lp) ? src[jj] : (unsigned short)0;
            }
        }
        __syncthreads();
        #pragma unroll
        for (int ks = 0; ks < 2; ++ks) {
            const int kc = ks * 32;
            FragU af[4];
            #pragma unroll
            for (int i = 0; i < 4; ++i)
                af[i].q = *(const uint4*)&As[(i * 16 + c) * 72 + kc + q * 8];
            const int koff = kc + q * 8;
            const int cioff = koff >> LG;
            const int k0 = koff & (KP - 1);
            const uint32_t* xr = (const uint32_t*)xraw + cioff * (WROW / 2);
            #pragma unroll
            for (int j = 0; j < JT; ++j) {
                int tt = w * (JT * 16) + j * 16 + c;
                int eoff = tt + k0;
                int d0 = eoff >> 1;
                unsigned sh = (unsigned)(eoff & 1) * 16u;
                uint32_t u0 = xr[d0], u1 = xr[d0 + 1], u2 = xr[d0 + 2],
                         u3 = xr[d0 + 3], u4 = xr[d0 + 4];
                FragU bf;
                bf.u[0] = __builtin_amdgcn_alignbit(u1, u0, sh);
                bf.u[1] = __builtin_amdgcn_alignbit(u2, u1, sh);
                bf.u[2] = __builtin_amdgcn_alignbit(u3, u2, sh);
                bf.u[3] = __builtin_amdgcn_alignbit(u4, u3, sh);
                #pragma unroll
                for (int i = 0; i < 4; ++i)
                    acc[i][j] = __builtin_amdgcn_mfma_f32_16x16x32_bf16(af[i].s, bf.s,
                                                                        acc[i][j], 0, 0, 0);
            }
        }
        __syncthreads();
    }
    if (pool_out) {
        #pragma unroll
        for (int i = 0; i < 4; ++i) {
            #pragma unroll
            for (int r = 0; r < 4; ++r) {
                int co = co0 + i * 16 + q * 4 + r;
                float bv = (co < Co) ? bias[co] : 0.f;
                float v = 0.f;
                #pragma unroll
                for (int j = 0; j < JT; ++j) {
                    int t = t0 + w * (JT * 16) + j * 16 + c;
                    if (t < Lout) v = fmaxf(v, fmaxf(acc[i][j][r] + bv, 0.f));
                }
                v = fmaxf(v, __shfl_xor(v, 1));
                v = fmaxf(v, __shfl_xor(v, 2));
                v = fmaxf(v, __shfl_xor(v, 4));
                v = fmaxf(v, __shfl_xor(v, 8));
                if (c == 0 && co < Co)
                    atomicMax((int*)&pool_out[(size_t)b * 1420 + pool_coloff + co],
                              __float_as_int(v));
            }
        }
    } else {
        #pragma unroll
        for (int i = 0; i < 4; ++i) {
            #pragma unroll
            for (int r = 0; r < 4; ++r) {
                int co = co0 + i * 16 + q * 4 + r;
                if (co >= Co) continue;
                float bv = bias[co];
                #pragma unroll
                for (int j = 0; j < JT; ++j) {
                    int t = t0 + w * (JT * 16) + j * 16 + c;
                    if (t < Lout) {
                        yout[((size_t)b * Co + co) * LoutPad + t] =
                            f2bf(fmaxf(acc[i][j][r] + bv, 0.f));
                    } else if (t < LoutPad) {
                        yout[((size_t)b * Co + co) * LoutPad + t] = 0;
                    }
                }
            }
        }
    }
}

// conv1 with fused embedding lookup (V <= 71). KP=8, Ci=64, ITILE=4, JT=2.
__device__ __forceinline__ void conv1e_body(const int* __restrict__ toks,
                                            const float* __restrict__ table, int V, int L,
                                            const unsigned short* __restrict__ Wt, int KK,
                                            const float* __restrict__ bias, int Co,
                                            unsigned short* __restrict__ yout,
                                            int Lout, int LoutPad,
                                            int b, int co0, int t0,
                                            unsigned short* As, unsigned short* xraw,
                                            unsigned short* tabT, int* tok_s) {
    constexpr int WROW = 144;
    const int tid = threadIdx.x;
    const int lane = tid & 63, w = tid >> 6, c = lane & 15, q = lane >> 4;
    for (int idx = tid; idx < 64 * V; idx += 256) {
        int ci = idx / V, v = idx % V;
        tabT[ci * 72 + v] = f2bf(table[(size_t)v * 64 + ci]);
    }
    for (int t = tid; t < WROW; t += 256) {
        int gt = t0 + t;
        tok_s[t] = (gt < L) ? toks[(size_t)b * L + gt] : 0;
    }
    __syncthreads();
    f32x4 acc[4][2];
    #pragma unroll
    for (int i = 0; i < 4; ++i)
        #pragma unroll
        for (int j = 0; j < 2; ++j) acc[i][j] = (f32x4){0.f, 0.f, 0.f, 0.f};
    const int row8 = tid >> 3, col8 = (tid & 7) * 8;
    for (int ch = 0; ch < 8; ++ch) {
        const int kkbase = ch * 64, ci0 = ch * 8;
        #pragma unroll
        for (int p = 0; p < 2; ++p) {
            int row = row8 + p * 32;
            *(uint4*)&As[row * 72 + col8] =
                *(const uint4*)&Wt[(size_t)(co0 + row) * KK + kkbase + col8];
        }
        for (int gi = tid; gi < 8 * WROW; gi += 256) {
            int ci = gi / WROW, t = gi % WROW;
            xraw[gi] = tabT[(ci0 + ci) * 72 + tok_s[t]];
        }
        __syncthreads();
        #pragma unroll
        for (int ks = 0; ks < 2; ++ks) {
            const int kc = ks * 32;
            FragU af[4];
            #pragma unroll
            for (int i = 0; i < 4; ++i)
                af[i].q = *(const uint4*)&As[(i * 16 + c) * 72 + kc + q * 8];
            const int koff = kc + q * 8;
            const int cioff = koff >> 3;
            const uint32_t* xr = (const uint32_t*)xraw + cioff * (WROW / 2);
            #pragma unroll
            for (int j = 0; j < 2; ++j) {
                int tt = w * 32 + j * 16 + c;
                int d0 = tt >> 1;
                unsigned sh = (unsigned)(tt & 1) * 16u;
                uint32_t u0 = xr[d0], u1 = xr[d0 + 1], u2 = xr[d0 + 2],
                         u3 = xr[d0 + 3], u4 = xr[d0 + 4];
                FragU bf;
                bf.u[0] = __builtin_amdgcn_alignbit(u1, u0, sh);
                bf.u[1] = __builtin_amdgcn_alignbit(u2, u1, sh);
                bf.u[2] = __builtin_amdgcn_alignbit(u3, u2, sh);
                bf.u[3] = __builtin_amdgcn_alignbit(u4, u3, sh);
                #pragma unroll
                for (int i = 0; i < 4; ++i)
                    acc[i][j] = __builtin_amdgcn_mfma_f32_16x16x32_bf16(af[i].s, bf.s,
                                                                        acc[i][j], 0, 0, 0);
            }
        }
        __syncthreads();
    }
    #pragma unroll
    for (int i = 0; i < 4; ++i) {
        #pragma unroll
        for (int r = 0; r < 4; ++r) {
            int co = co0 + i * 16 + q * 4 + r;
            if (co >= Co) continue;
            float bv = bias[co];
            #pragma unroll
            for (int j = 0; j < 2; ++j) {
                int t = t0 + w * 32 + j * 16 + c;
                if (t < Lout) {
                    yout[((size_t)b * Co + co) * LoutPad + t] =
                        f2bf(fmaxf(acc[i][j][r] + bv, 0.f));
                } else if (t < LoutPad) {
                    yout[((size_t)b * Co + co) * LoutPad + t] = 0;
                }
            }
        }
    }
}

// conv1 dual: z<64 protein (x in [0,8)), z>=64 drug (x==0). grid (8,1,128)
__global__ __launch_bounds__(256) void conv1_dual(
    const int* __restrict__ ptoks, const float* __restrict__ ptable,
    const unsigned short* __restrict__ WtP1, const float* __restrict__ pb1,
    unsigned short* __restrict__ y1p,
    const int* __restrict__ dtoks, const float* __restrict__ dtable,
    const unsigned short* __restrict__ WtD1, const float* __restrict__ db1,
    unsigned short* __restrict__ y1d) {
    __shared__ __align__(16) unsigned short As[64 * 72];
    __shared__ __align__(16) unsigned short xraw[8 * 144];
    __shared__ unsigned short tabT[64 * 72];
    __shared__ int tok_s[144];
    int z = blockIdx.z;
    if (z < 64) {
        conv1e_body(ptoks, ptable, 26, 1000, WtP1, 512, pb1, 40, y1p, 997, 1000,
                    z, 0, blockIdx.x * 128, As, xraw, tabT, tok_s);
    } else {
        if (blockIdx.x > 0) return;
        conv1e_body(dtoks, dtable, 71, 100, WtD1, 512, db1, 40, y1d, 97, 104,
                    z - 64, 0, 0, As, xraw, tabT, tok_s);
    }
}

// m2: conv2 (1152 ids: 1024 protein + 128 drug) + sk_stage1 rider (768 ids)
__global__ __launch_bounds__(256) void m2_k(int nconv,
    const unsigned short* __restrict__ y1p, const unsigned short* __restrict__ WtP2,
    const float* __restrict__ pb2, unsigned short* __restrict__ y2p,
    const unsigned short* __restrict__ y1d, const unsigned short* __restrict__ WtD2,
    const float* __restrict__ db2, unsigned short* __restrict__ y2d,
    const unsigned short* __restrict__ Ad, const unsigned short* __restrict__ WdS,
    float* __restrict__ Ud,
    const unsigned short* __restrict__ Ap, const unsigned short* __restrict__ WpS,
    float* __restrict__ Up) {
    __shared__ __align__(16) unsigned short As[64 * 72];
    __shared__ __align__(16) unsigned short xraw[8 * 144];
    int id = blockIdx.x;
    if (id < nconv) {
        if (id < 1024) {
            int b = id >> 4, r = id & 15;
            conv_body<8, 2>(y1p, 40, 1000, WtP2, 320, 5, pb2, 80, y2p, 990, 992,
                            nullptr, 0, b, (r >> 3) * 64, (r & 7) * 128, As, xraw);
        } else {
            int t = id - 1024;
            conv_body<8, 2>(y1d, 40, 104, WtD2, 320, 5, db2, 80, y2d, 92, 96,
                            nullptr, 0, t >> 1, (t & 1) * 64, 0, As, xraw);
        }
    } else {
        int t = id - nconv;
        int bx = t & 15, by = (t >> 4) & 7, bz = t >> 7;
        if (bz < 3) {
            sk_body(Ap, 2208, WpS, 2208, 2208, 8, 0.5f, Up, 1024, 0, 1000, bx, by, bz);
        } else {
            if (bx >= 2) return;
            sk_body(Ad, 1248, WdS, 1248, 1248, 8, 0.5f, Ud, 112, 0, 100, bx, by, bz - 3);
        }
    }
}

// m3: conv3 (1728 ids: 1536 protein + 192 drug) + ep rider (852 ids)
__global__ __launch_bounds__(256) void m3_k(int nconv,
    const unsigned short* __restrict__ y2p, const unsigned short* __restrict__ WtP3,
    const float* __restrict__ pb3, float* __restrict__ pair,
    const unsigned short* __restrict__ y2d, const unsigned short* __restrict__ WtD3,
    const float* __restrict__ db3,
    const float* __restrict__ Ud, const float* __restrict__ Up,
    const float* __restrict__ RHO,
    const float* __restrict__ bd, const float* __restrict__ bp,
    unsigned short* __restrict__ A2d, unsigned short* __restrict__ A2p) {
    __shared__ __align__(16) unsigned short As[64 * 72];
    __shared__ __align__(16) unsigned short xraw[8 * 144];
    int id = blockIdx.x;
    if (id < nconv) {
        if (id < 1536) {
            int b = id / 24, r = id % 24;
            conv_body<16, 2>(y2p, 80, 992, WtP3, 1280, 20, pb3, 160, nullptr, 979, 0,
                             pair, 160, b, (r >> 3) * 64, (r & 7) * 128, As, xraw);
        } else {
            int t = id - 1536;
            conv_body<8, 2>(y2d, 80, 96, WtD3, 640, 10, db3, 160, nullptr, 85, 0,
                            pair, 0, t / 3, (t % 3) * 64, 0, As, xraw);
        }
    } else {
        int idx = (id - nconv) * 256 + threadIdx.x;
        ep_item(idx, Ud, Up, RHO, bd, bp, A2d, A2p);
    }
}

// stage-2 skinny GEMM (R8-identical). grid (16,8,2)
__global__ __launch_bounds__(256) void sk_stage2(const unsigned short* __restrict__ A2d,
                                                 const unsigned short* __restrict__ WdS,
                                                 const unsigned short* __restrict__ A2p,
                                                 const unsigned short* __restrict__ WpS,
                                                 float* __restrict__ pair) {
    int z = blockIdx.z;
    if (z == 0) {
        sk_body(A2p, 2208, WpS, 2208, 2208, 8, 0.5f, pair, 1420, 420, 1000,
                blockIdx.x, blockIdx.y, 0);
    } else {
        if (blockIdx.x >= 2) return;
        sk_body(A2d, 1248, WdS, 1248, 1248, 8, 0.5f, pair, 1420, 320, 100,
                blockIdx.x, blockIdx.y, 0);
    }
}

// ---------------------------------------------------------------------------
// fp32 NT-SGEMM (FC head), split-K atomic; optional leaky(bias) on A-load.
__global__ __launch_bounds__(256) void gemm_nt(const float* __restrict__ A, int lda,
                                               const float* __restrict__ Aep_b,
                                               const float* __restrict__ Bm,
                                               float* __restrict__ Cout,
                                               int M, int N, int K, int KC) {
    const int m0 = blockIdx.x * 64, n0 = blockIdx.y * 64, s = blockIdx.z;
    const int tid = threadIdx.x, ty = tid >> 4, tx = tid & 15;
    __shared__ __align__(16) float As[16][68];
    __shared__ __align__(16) float Bs[16][68];
    float acc[4][4] = {};
    const int kbeg = s * KC, kend = min(K, kbeg + KC);
    for (int k0 = kbeg; k0 < kend; k0 += 16) {
        int colk = k0 + tx;
        bool kok = colk < kend;
        #pragma unroll
        for (int qq = 0; qq < 4; ++qq) {
            int mi = ty + qq * 16;
            float va = 0.f;
            if (kok && (m0 + mi) < M) {
                va = A[(size_t)(m0 + mi) * lda + colk];
                if (Aep_b) {
                    va += Aep_b[colk];
                    va = va >= 0.f ? va : 0.01f * va;
                }
            }
            As[tx][mi] = va;
            Bs[tx][mi] = (kok && (n0 + mi) < N) ? Bm[(size_t)(n0 + mi) * K + colk] : 0.f;
        }
        __syncthreads();
        #pragma unroll
        for (int kk = 0; kk < 16; ++kk) {
            float4 a4 = *(const float4*)&As[kk][ty * 4];
            float4 b4 = *(const float4*)&Bs[kk][tx * 4];
            float av[4] = {a4.x, a4.y, a4.z, a4.w};
            float bv[4] = {b4.x, b4.y, b4.z, b4.w};
            #pragma unroll
            for (int i = 0; i < 4; ++i)
                #pragma unroll
                for (int j = 0; j < 4; ++j)
                    acc[i][j] = fmaf(av[i], bv[j], acc[i][j]);
        }
        __syncthreads();
    }
    #pragma unroll
    for (int i = 0; i < 4; ++i) {
        int m = m0 + ty * 4 + i;
        if (m >= M) continue;
        #pragma unroll
        for (int j = 0; j < 4; ++j) {
            int n = n0 + tx * 4 + j;
            if (n >= N) continue;
            atomicAdd(&Cout[(size_t)m * N + n], acc[i][j]);
        }
    }
}

__global__ void out_k(const float* __restrict__ cf3, const float* __restrict__ b3,
                      const float* __restrict__ W, const float* __restrict__ bias,
                      float* __restrict__ out) {
    int tid = threadIdx.x;
    if (tid >= 128) return;
    int b = tid >> 1, n = tid & 1;
    const float* hr = cf3 + (size_t)b * 512;
    const float* wr = W + (size_t)n * 512;
    float a = 0.f;
    for (int k = 0; k < 512; ++k) {
        float v = hr[k] + b3[k];
        v = v >= 0.f ? v : 0.01f * v;
        a = fmaf(v, wr[k], a);
    }
    out[b * 2 + n] = a + bias[n];
}

// ---------------------------------------------------------------------------
static inline int kc_of(int K, int S) { return ((K + S * 16 - 1) / (S * 16)) * 16; }
static inline dim3 g1d(int n) { return dim3((n + 255) / 256); }

extern "C" void kernel_launch(void* const* d_in, const int* in_sizes, int n_in,
                              void* d_out, int out_size, void* d_ws, size_t ws_size,
                              hipStream_t stream) {
    const int* drug_tokens       = (const int*)d_in[0];
    const int* protein_tokens    = (const int*)d_in[1];
    const int* drug_node_tokens  = (const int*)d_in[2];
    const int* protein_node_toks = (const int*)d_in[3];
    const int* ddi_edges         = (const int*)d_in[4];
    const int* ppi_edges         = (const int*)d_in[5];
    const int* dpi_edges         = (const int*)d_in[6];
    const float* drug_embed      = (const float*)d_in[7];
    const float* protein_embed   = (const float*)d_in[8];
    const float* dW1 = (const float*)d_in[9];  const float* db1 = (const float*)d_in[10];
    const float* dW2 = (const float*)d_in[11]; const float* db2 = (const float*)d_in[12];
    const float* dW3 = (const float*)d_in[13]; const float* db3 = (const float*)d_in[14];
    const float* pW1 = (const float*)d_in[15]; const float* pb1 = (const float*)d_in[16];
    const float* pW2 = (const float*)d_in[17]; const float* pb2 = (const float*)d_in[18];
    const float* pW3 = (const float*)d_in[19]; const float* pb3 = (const float*)d_in[20];
    const float* drug_node_table = (const float*)d_in[21];
    const float* prot_node_table = (const float*)d_in[22];
    const float* ddi_Wl = (const float*)d_in[23]; const float* ddi_bl = (const float*)d_in[24];
    const float* ddi_Wr = (const float*)d_in[25];
    const float* ppi_Wl = (const float*)d_in[26]; const float* ppi_bl = (const float*)d_in[27];
    const float* ppi_Wr = (const float*)d_in[28];
    const float* dpi_Wl = (const float*)d_in[29]; const float* dpi_bl = (const float*)d_in[30];
    const float* dpi_Wr = (const float*)d_in[31];
    const float* pdi_Wl = (const float*)d_in[32]; const float* pdi_bl = (const float*)d_in[33];
    const float* pdi_Wr = (const float*)d_in[34];
    const float* fc1_W = (const float*)d_in[35]; const float* fc1_b = (const float*)d_in[36];
    const float* fc2_W = (const float*)d_in[37]; const float* fc2_b = (const float*)d_in[38];
    const float* fc3_W = (const float*)d_in[39]; const float* fc3_b = (const float*)d_in[40];
    const float* out_W = (const float*)d_in[41]; const float* out_b = (const float*)d_in[42];

    float* outp = (float*)d_out;
    if (ws_size < NEED_FB) {
        zero32_k<<<g1d(out_size), 256, 0, stream>>>((uint32_t*)outp, out_size);
        return;
    }
    const bool full = (ws_size >= NEED_FULL);

    char* wsb = (char*)d_ws;
    float* pair = (float*)(wsb + O_PAIR);
    float* cf1 = (float*)(wsb + O_CF1); float* cf2 = (float*)(wsb + O_CF2);
    float* cf3 = (float*)(wsb + O_CF3);
    float* bd = (float*)(wsb + O_BD); float* bp = (float*)(wsb + O_BP);
    unsigned short* WdS  = (unsigned short*)(wsb + O_WDS);
    unsigned short* WpS  = (unsigned short*)(wsb + O_WPS);
    unsigned short* WtP1 = (unsigned short*)(wsb + O_WTP1);
    unsigned short* WtP2 = (unsigned short*)(wsb + O_WTP2);
    unsigned short* WtP3 = (unsigned short*)(wsb + O_WTP3);
    unsigned short* WtD1 = (unsigned short*)(wsb + O_WTD1);
    unsigned short* WtD2 = (unsigned short*)(wsb + O_WTD2);
    unsigned short* WtD3 = (unsigned short*)(wsb + O_WTD3);
    unsigned short* Ad  = (unsigned short*)(wsb + A_AD);
    unsigned short* Ap  = (unsigned short*)(wsb + A_AP);
    unsigned short* A2d = (unsigned short*)(wsb + A_A2D);
    unsigned short* A2p = (unsigned short*)(wsb + A_A2P);
    float* Ud  = (float*)(wsb + A_UD);
    float* Up  = (float*)(wsb + A_UP);
    float* RHO = (float*)(wsb + A_RHO);
    size_t cbase = full ? GNN_END : AR;  // conv buffers: non-aliased iff full
    unsigned short* y2p = (unsigned short*)(wsb + cbase);
    unsigned short* y1p = (unsigned short*)(wsb + cbase + SZ_Y2P);
    unsigned short* y1d = (unsigned short*)(wsb + cbase + SZ_Y2P + SZ_Y1P);
    unsigned short* y2d = (unsigned short*)(wsb + cbase + SZ_Y2P + SZ_Y1P + SZ_Y1D);

    // 1) prep: weights + biases + pair biasfill/zero + cf zero + GNN zero
    prep_k<<<g1d((int)Q17), 256, 0, stream>>>(bd, bp, WdS, WpS,
                                              WtP1, WtP2, WtP3, WtD1, WtD2, WtD3,
                                              pair, cf1, (uint32_t*)(wsb + A_AD),
                                              ddi_Wl, ddi_bl, ddi_Wr,
                                              ppi_Wl, ppi_bl, ppi_Wr,
                                              dpi_Wl, dpi_bl, dpi_Wr,
                                              pdi_Wl, pdi_bl, pdi_Wr,
                                              dW1, dW2, dW3, pW1, pW2, pW3);

    // 2) GNN front-end (standalone — lean conv kernels must not inherit its
    //    29.5KB/144-VGPR footprint; R10 measured that union at -2x occupancy)
    gnn_front_k<<<dim3(2, 64), 256, 0, stream>>>(ddi_edges, ppi_edges, dpi_edges,
                                                 drug_node_tokens, protein_node_toks,
                                                 drug_node_table, prot_node_table,
                                                 RHO, Ad, Ap);

    if (full) {
        // 3) conv1 ; 4) conv2 + sk1 rider ; 5) conv3 + ep rider ; 6) sk2
        conv1_dual<<<dim3(8, 1, 128), 256, 0, stream>>>(protein_tokens, protein_embed,
                                                        WtP1, pb1, y1p,
                                                        drug_tokens, drug_embed,
                                                        WtD1, db1, y1d);
        m2_k<<<dim3(1152 + 768), 256, 0, stream>>>(1152,
            y1p, WtP2, pb2, y2p, y1d, WtD2, db2, y2d, Ad, WdS, Ud, Ap, WpS, Up);
        m3_k<<<dim3(1728 + 852), 256, 0, stream>>>(1728,
            y2p, WtP3, pb3, pair, y2d, WtD3, db3, Ud, Up, RHO, bd, bp, A2d, A2p);
        sk_stage2<<<dim3(16, 8, 2), 256, 0, stream>>>(A2d, WdS, A2p, WpS, pair);
    } else {
        // serial fallback (R8-equivalent ordering; conv aliases dead GNN region)
        m2_k<<<dim3(768), 256, 0, stream>>>(0,
            y1p, WtP2, pb2, y2p, y1d, WtD2, db2, y2d, Ad, WdS, Ud, Ap, WpS, Up);
        m3_k<<<dim3(852), 256, 0, stream>>>(0,
            y2p, WtP3, pb3, pair, y2d, WtD3, db3, Ud, Up, RHO, bd, bp, A2d, A2p);
        sk_stage2<<<dim3(16, 8, 2), 256, 0, stream>>>(A2d, WdS, A2p, WpS, pair);
        conv1_dual<<<dim3(8, 1, 128), 256, 0, stream>>>(protein_tokens, protein_embed,
                                                        WtP1, pb1, y1p,
                                                        drug_tokens, drug_embed,
                                                        WtD1, db1, y1d);
        m2_k<<<dim3(1152), 256, 0, stream>>>(1152,
            y1p, WtP2, pb2, y2p, y1d, WtD2, db2, y2d, Ad, WdS, Ud, Ap, WpS, Up);
        m3_k<<<dim3(1728), 256, 0, stream>>>(1728,
            y2p, WtP3, pb3, pair, y2d, WtD3, db3, Ud, Up, RHO, bd, bp, A2d, A2p);
    }

    // FC head (fp32, split-K 16; leaky+bias fused into next gemm's A-load)
    gemm_nt<<<dim3(1, 16, 16), 256, 0, stream>>>(pair, 1420, nullptr, fc1_W, cf1,
                                                 64, 1024, 1420, kc_of(1420, 16));
    gemm_nt<<<dim3(1, 16, 16), 256, 0, stream>>>(cf1, 1024, fc1_b, fc2_W, cf2,
                                                 64, 1024, 1024, kc_of(1024, 16));
    gemm_nt<<<dim3(1, 8, 16), 256, 0, stream>>>(cf2, 1024, fc2_b, fc3_W, cf3,
                                                64, 512, 1024, kc_of(1024, 16));
    out_k<<<dim3(1), 128, 0, stream>>>(cf3, fc3_b, out_W, out_b, outp);
}